// Round 2
// baseline (664.350 us; speedup 1.0000x reference)
//
#include <hip/hip_runtime.h>
#include <stdint.h>

typedef unsigned short u16;
typedef unsigned int u32;

#define S_LEN 4096
#define EMB 2048
#define NH 16
#define HD 128
#define HDTOT 2048
#define T_TILES 32
#define KANCH 8
#define NSPLIT 3
#define NROWS 65536  // NH * T_TILES * 128
#define SM_SCALE 0.088388347648318447f

typedef __bf16 bf16x8 __attribute__((ext_vector_type(8)));
typedef float f32x4 __attribute__((ext_vector_type(4)));

typedef const __attribute__((address_space(1))) u32 ga_u32;
typedef __attribute__((address_space(3))) u32 lds_u32;

__device__ __forceinline__ u16 f2bf(float f) {
  u32 b = __builtin_bit_cast(u32, f);
  b = (b + 0x7FFFu + ((b >> 16) & 1u)) >> 16;
  return (u16)b;
}
__device__ __forceinline__ float bf2f(u16 u) {
  return __builtin_bit_cast(float, ((u32)u) << 16);
}
__device__ __forceinline__ f32x4 mfma16(bf16x8 a, bf16x8 b, f32x4 c) {
  return __builtin_amdgcn_mfma_f32_16x16x32_bf16(a, b, c, 0, 0, 0);
}

// ---------------- x: fp32 -> bf16 ----------------
__global__ __launch_bounds__(256) void k_convert_x(const float* __restrict__ x,
                                                   u16* __restrict__ xb) {
  int i = (blockIdx.x * 256 + threadIdx.x) * 4;
  float4 v = *(const float4*)(x + i);
  ushort4 o;
  o.x = f2bf(v.x); o.y = f2bf(v.y); o.z = f2bf(v.z); o.w = f2bf(v.w);
  *(ushort4*)(xb + i) = o;
}

// ------- weights: [K=2048][N=2048] fp32 -> [N][K] bf16 (B^T for gemm) -------
__global__ __launch_bounds__(256) void k_transpose_w(
    const float* __restrict__ w0, const float* __restrict__ w1,
    const float* __restrict__ w2, const float* __restrict__ w3,
    u16* __restrict__ o0, u16* __restrict__ o1,
    u16* __restrict__ o2, u16* __restrict__ o3) {
  const float* w; u16* o;
  if (blockIdx.z == 0)      { w = w0; o = o0; }
  else if (blockIdx.z == 1) { w = w1; o = o1; }
  else if (blockIdx.z == 2) { w = w2; o = o2; }
  else                      { w = w3; o = o3; }
  __shared__ float tile[64][68];
  int n0 = blockIdx.x * 64, k0 = blockIdx.y * 64;
  int tid = threadIdx.x;
  int r = tid >> 4, cq = (tid & 15) << 2;
  for (int p = 0; p < 4; ++p) {
    float4 v = *(const float4*)(w + (size_t)(k0 + r + p * 16) * EMB + n0 + cq);
    tile[r + p * 16][cq + 0] = v.x;
    tile[r + p * 16][cq + 1] = v.y;
    tile[r + p * 16][cq + 2] = v.z;
    tile[r + p * 16][cq + 3] = v.w;
  }
  __syncthreads();
  for (int p = 0; p < 4; ++p) {
    int rn = r + p * 16;
    ushort4 u;
    u.x = f2bf(tile[cq + 0][rn]);
    u.y = f2bf(tile[cq + 1][rn]);
    u.z = f2bf(tile[cq + 2][rn]);
    u.w = f2bf(tile[cq + 3][rn]);
    *(ushort4*)(o + (size_t)(n0 + rn) * EMB + k0 + cq) = u;
  }
}

// ------- v: [S][HDTOT] bf16 -> vT [HDTOT][S] bf16 -------
__global__ __launch_bounds__(256) void k_transpose_v(const u16* __restrict__ v,
                                                     u16* __restrict__ vt) {
  __shared__ u16 tile[64][72];
  int n0 = blockIdx.x * 64, s0 = blockIdx.y * 64;
  int tid = threadIdx.x;
  int r = tid >> 4, cq = (tid & 15) << 2;
  for (int p = 0; p < 4; ++p) {
    ushort4 u = *(const ushort4*)(v + (size_t)(s0 + r + p * 16) * HDTOT + n0 + cq);
    tile[r + p * 16][cq + 0] = u.x;
    tile[r + p * 16][cq + 1] = u.y;
    tile[r + p * 16][cq + 2] = u.z;
    tile[r + p * 16][cq + 3] = u.w;
  }
  __syncthreads();
  for (int p = 0; p < 4; ++p) {
    int rn = r + p * 16;
    ushort4 o;
    o.x = tile[cq + 0][rn];
    o.y = tile[cq + 1][rn];
    o.z = tile[cq + 2][rn];
    o.w = tile[cq + 3][rn];
    *(ushort4*)(vt + (size_t)(n0 + rn) * S_LEN + s0 + cq) = o;
  }
}

// ------- m97-style bf16 GEMM: C[M][N] = A[M][K] * Bt[N][K]^T -------
template <bool BF16OUT>
__global__ __launch_bounds__(256) void k_gemm(const u16* __restrict__ A,
                                              const u16* __restrict__ Bt,
                                              void* __restrict__ Cv,
                                              int M, int N, int K) {
  __shared__ __align__(16) u16 As[128 * 32];
  __shared__ __align__(16) u16 Bs[128 * 32];
  const int tid = threadIdx.x;
  const int lane = tid & 63, wave = tid >> 6;
  const int quad = lane >> 4, l16 = lane & 15;
  const int m0 = blockIdx.y * 128, n0 = blockIdx.x * 128;
  const int wm = (wave >> 1) * 64, wn = (wave & 1) * 64;
  f32x4 acc[4][4] = {};

  const int flat0 = wave * 1024 + lane * 16;  // byte offset within 8KB tile
  for (int kt = 0; kt < K; kt += 32) {
    for (int half = 0; half < 2; ++half) {
      int flat = flat0 + half * 4096;
      int row = flat >> 6, colb = flat & 63;
      const char* ga = (const char*)A + ((size_t)(m0 + row) * K + kt) * 2 + colb;
      const char* gb = (const char*)Bt + ((size_t)(n0 + row) * K + kt) * 2 + colb;
      int loff = wave * 1024 + half * 4096;  // wave-uniform LDS byte offset
      __builtin_amdgcn_global_load_lds((ga_u32*)ga, (lds_u32*)((char*)As + loff), 16, 0, 0);
      __builtin_amdgcn_global_load_lds((ga_u32*)gb, (lds_u32*)((char*)Bs + loff), 16, 0, 0);
    }
    __syncthreads();
    bf16x8 af[4], bfr[4];
    for (int mt = 0; mt < 4; ++mt)
      af[mt] = *(const bf16x8*)(As + (wm + mt * 16 + l16) * 32 + quad * 8);
    for (int nt = 0; nt < 4; ++nt)
      bfr[nt] = *(const bf16x8*)(Bs + (wn + nt * 16 + l16) * 32 + quad * 8);
    for (int mt = 0; mt < 4; ++mt)
      for (int nt = 0; nt < 4; ++nt)
        acc[mt][nt] = mfma16(af[mt], bfr[nt], acc[mt][nt]);
    __syncthreads();
  }
  for (int mt = 0; mt < 4; ++mt) {
    int row = m0 + wm + mt * 16 + quad * 4;
    for (int nt = 0; nt < 4; ++nt) {
      int col = n0 + wn + nt * 16 + l16;
      for (int r = 0; r < 4; ++r) {
        if (BF16OUT)
          ((u16*)Cv)[(size_t)(row + r) * N + col] = f2bf(acc[mt][nt][r]);
        else
          ((float*)Cv)[(size_t)(row + r) * N + col] = acc[mt][nt][r];
      }
    }
  }
}

// ------- RoPE (half-split) applied in-place to q and k -------
__global__ __launch_bounds__(256) void k_rope(u16* __restrict__ q, u16* __restrict__ k,
                                              const float* __restrict__ ang) {
  int gid = blockIdx.x * 256 + threadIdx.x;  // S*NH*64
  int s = gid >> 10;
  int h = (gid >> 6) & (NH - 1);
  int d = gid & 63;
  float a = ang[s * 64 + d];
  float sn, cs;
  __sincosf(a, &sn, &cs);
  size_t base = (size_t)s * HDTOT + h * HD + d;
  float q1 = bf2f(q[base]), q2 = bf2f(q[base + 64]);
  q[base] = f2bf(q1 * cs - q2 * sn);
  q[base + 64] = f2bf(q2 * cs + q1 * sn);
  float k1 = bf2f(k[base]), k2 = bf2f(k[base + 64]);
  k[base] = f2bf(k1 * cs - k2 * sn);
  k[base + 64] = f2bf(k2 * cs + k1 * sn);
}

// ------- attention helpers: XOR-swizzled 128x128 bf16 LDS tiles -------
__device__ __forceinline__ void stage128(u16* __restrict__ sbuf, const u16* __restrict__ g,
                                         int gpitch, int tid) {
  for (int p = 0; p < 8; ++p) {
    int flat = p * 2048 + tid * 8;
    int r = flat >> 7, c = flat & 127;
    uint4 val = *(const uint4*)(g + (size_t)r * gpitch + c);
    *(uint4*)(sbuf + r * 128 + (((c >> 3) ^ (r & 15)) << 3)) = val;
  }
}
__device__ __forceinline__ bf16x8 ldsfrag(const u16* __restrict__ sbuf, int r, int cb) {
  return *(const bf16x8*)(sbuf + r * 128 + (((cb ^ (r & 15)) << 3)));
}

// ------- block-sparse flash attention, split-j (flash-decoding style) -------
// grid: (T, NH, NSPLIT). Split sp handles j in [sp*3, sp*3+3); j==8 is the
// local (diagonal) tile. Each block writes a NORMALIZED partial O (bf16) plus
// per-row (m, l) fp32; k_combine merges the NSPLIT partials exactly.
__global__ __launch_bounds__(256, 2) void k_attn(const u16* __restrict__ q,
                                                 const u16* __restrict__ k,
                                                 const u16* __restrict__ vt,
                                                 const int* __restrict__ anch,
                                                 u16* __restrict__ pO0,
                                                 u16* __restrict__ pO1,
                                                 u16* __restrict__ pO2,
                                                 float* __restrict__ pM,
                                                 float* __restrict__ pL) {
  __shared__ __align__(16) u16 bufK[128 * 128];  // Q -> K_j -> P overlay
  __shared__ __align__(16) u16 bufV[128 * 128];  // V_j^T
  const int t = blockIdx.x, h = blockIdx.y, sp = blockIdx.z;
  const int tid = threadIdx.x;
  const int lane = tid & 63, wave = tid >> 6;
  const int quad = lane >> 4, l16 = lane & 15;

  // stage Q tile, pull A-frags to registers
  stage128(bufK, q + (size_t)(t * 128) * HDTOT + h * HD, HDTOT, tid);
  __syncthreads();
  bf16x8 qf[2][4];
  for (int mt = 0; mt < 2; ++mt)
    for (int ks = 0; ks < 4; ++ks)
      qf[mt][ks] = ldsfrag(bufK, wave * 32 + mt * 16 + l16, ks * 4 + quad);
  __syncthreads();

  f32x4 oacc[2][8] = {};
  float mrow[2][4], lrow[2][4];
  for (int mt = 0; mt < 2; ++mt)
    for (int r = 0; r < 4; ++r) { mrow[mt][r] = -1e30f; lrow[mt][r] = 0.f; }

  for (int j = sp * 3; j < sp * 3 + 3; ++j) {
    int tj = (j < KANCH) ? anch[((h * T_TILES) + t) * KANCH + j] : t;
    if (tj > t) continue;  // fully future-masked: exact zero contribution

    stage128(bufK, k + (size_t)(tj * 128) * HDTOT + h * HD, HDTOT, tid);
    stage128(bufV, vt + (size_t)(h * HD) * S_LEN + tj * 128, S_LEN, tid);
    __syncthreads();

    // S = Q K^T  (wave owns 32 q-rows x 128 keys)
    f32x4 sacc[2][8] = {};
    for (int ks = 0; ks < 4; ++ks)
      for (int nt = 0; nt < 8; ++nt) {
        bf16x8 bk = ldsfrag(bufK, nt * 16 + l16, ks * 4 + quad);
        sacc[0][nt] = mfma16(qf[0][ks], bk, sacc[0][nt]);
        sacc[1][nt] = mfma16(qf[1][ks], bk, sacc[1][nt]);
      }
    __syncthreads();  // all waves done reading K; bufK free for P overlay

    const bool diag = (tj == t);
    for (int mt = 0; mt < 2; ++mt) {
      float rmax[4] = {-1e30f, -1e30f, -1e30f, -1e30f};
      for (int nt = 0; nt < 8; ++nt) {
        f32x4 s4 = sacc[mt][nt];
        for (int r = 0; r < 4; ++r) {
          float sv = s4[r] * SM_SCALE;
          if (diag && (nt * 16 + l16 > wave * 32 + mt * 16 + quad * 4 + r)) sv = -1e30f;
          s4[r] = sv;
          rmax[r] = fmaxf(rmax[r], sv);
        }
        sacc[mt][nt] = s4;
      }
      float alpha[4];
      for (int r = 0; r < 4; ++r) {
        float rm = rmax[r];
        rm = fmaxf(rm, __shfl_xor(rm, 1));
        rm = fmaxf(rm, __shfl_xor(rm, 2));
        rm = fmaxf(rm, __shfl_xor(rm, 4));
        rm = fmaxf(rm, __shfl_xor(rm, 8));
        float mnew = fmaxf(mrow[mt][r], rm);
        alpha[r] = __expf(mrow[mt][r] - mnew);
        mrow[mt][r] = mnew;
      }
      float rsum[4] = {0.f, 0.f, 0.f, 0.f};
      for (int nt = 0; nt < 8; ++nt) {
        f32x4 s4 = sacc[mt][nt];
        for (int r = 0; r < 4; ++r) {
          float p = __expf(s4[r] - mrow[mt][r]);
          s4[r] = p;
          rsum[r] += p;
        }
        sacc[mt][nt] = s4;
      }
      for (int r = 0; r < 4; ++r) {
        float rs = rsum[r];
        rs += __shfl_xor(rs, 1);
        rs += __shfl_xor(rs, 2);
        rs += __shfl_xor(rs, 4);
        rs += __shfl_xor(rs, 8);
        lrow[mt][r] = lrow[mt][r] * alpha[r] + rs;
      }
      // rescale O and write P (bf16) into bufK overlay
      for (int nt = 0; nt < 8; ++nt) {
        f32x4 o4 = oacc[mt][nt];
        f32x4 s4 = sacc[mt][nt];
        for (int r = 0; r < 4; ++r) {
          o4[r] *= alpha[r];
          int qrow = wave * 32 + mt * 16 + quad * 4 + r;
          int c = nt * 16 + l16;
          bufK[qrow * 128 + ((((c >> 3) ^ (qrow & 15)) << 3)) + (c & 7)] = f2bf(s4[r]);
        }
        oacc[mt][nt] = o4;
      }
    }
    __syncthreads();  // P visible in A-layout order

    // O += P V  (A-frags from P overlay, B-frags from V^T)
    for (int ks = 0; ks < 4; ++ks) {
      bf16x8 pa0 = ldsfrag(bufK, wave * 32 + l16, ks * 4 + quad);
      bf16x8 pa1 = ldsfrag(bufK, wave * 32 + 16 + l16, ks * 4 + quad);
      for (int nt = 0; nt < 8; ++nt) {
        bf16x8 bv = ldsfrag(bufV, nt * 16 + l16, ks * 4 + quad);
        oacc[0][nt] = mfma16(pa0, bv, oacc[0][nt]);
        oacc[1][nt] = mfma16(pa1, bv, oacc[1][nt]);
      }
    }
    __syncthreads();  // done reading bufK/bufV before next staging
  }

  // write normalized partial O (bf16) + per-row m,l (fp32)
  u16* __restrict__ pO = (sp == 0) ? pO0 : ((sp == 1) ? pO1 : pO2);
  const int rowbase = (h * T_TILES + t) * 128;
  if (l16 == 0) {
    for (int mt = 0; mt < 2; ++mt)
      for (int r = 0; r < 4; ++r) {
        int rr = rowbase + wave * 32 + mt * 16 + quad * 4 + r;
        pM[sp * NROWS + rr] = mrow[mt][r];
        pL[sp * NROWS + rr] = lrow[mt][r];
      }
  }
  for (int mt = 0; mt < 2; ++mt)
    for (int r = 0; r < 4; ++r) {
      float l = lrow[mt][r];
      float inv = (l > 0.f) ? (1.0f / l) : 0.f;
      size_t orow = (size_t)(rowbase + wave * 32 + mt * 16 + quad * 4 + r) * 128;
      for (int nt = 0; nt < 8; ++nt)
        pO[orow + nt * 16 + l16] = f2bf(oacc[mt][nt][r] * inv);
    }
}

// ------- combine NSPLIT partials: exact log-sum-exp merge -------
__global__ __launch_bounds__(256) void k_combine(const u16* __restrict__ pO0,
                                                 const u16* __restrict__ pO1,
                                                 const u16* __restrict__ pO2,
                                                 const float* __restrict__ pM,
                                                 const float* __restrict__ pL,
                                                 u16* __restrict__ out) {
  int gid = blockIdx.x * 256 + threadIdx.x;  // NROWS * 16 threads
  int row = gid >> 4;           // (h*T + t)*128 + r
  int cb = (gid & 15) << 3;     // 8-dim chunk
  int h = row >> 12;
  int tr = row & 4095;          // t*128 + r  == sequence position
  float m0 = pM[row], m1 = pM[NROWS + row], m2 = pM[2 * NROWS + row];
  float l0 = pL[row], l1 = pL[NROWS + row], l2 = pL[2 * NROWS + row];
  float M = fmaxf(fmaxf(m0, m1), m2);
  float w0 = l0 * __expf(m0 - M);
  float w1 = l1 * __expf(m1 - M);
  float w2 = l2 * __expf(m2 - M);
  float invL = 1.0f / (w0 + w1 + w2);
  w0 *= invL; w1 *= invL; w2 *= invL;
  size_t po = (size_t)row * 128 + cb;
  ushort4 a0 = *(const ushort4*)(pO0 + po);
  ushort4 a1 = *(const ushort4*)(pO0 + po + 4);
  ushort4 b0 = *(const ushort4*)(pO1 + po);
  ushort4 b1 = *(const ushort4*)(pO1 + po + 4);
  ushort4 c0 = *(const ushort4*)(pO2 + po);
  ushort4 c1 = *(const ushort4*)(pO2 + po + 4);
  u16* o = out + (size_t)tr * HDTOT + h * HD + cb;
  ushort4 r0, r1;
  r0.x = f2bf(w0 * bf2f(a0.x) + w1 * bf2f(b0.x) + w2 * bf2f(c0.x));
  r0.y = f2bf(w0 * bf2f(a0.y) + w1 * bf2f(b0.y) + w2 * bf2f(c0.y));
  r0.z = f2bf(w0 * bf2f(a0.z) + w1 * bf2f(b0.z) + w2 * bf2f(c0.z));
  r0.w = f2bf(w0 * bf2f(a0.w) + w1 * bf2f(b0.w) + w2 * bf2f(c0.w));
  r1.x = f2bf(w0 * bf2f(a1.x) + w1 * bf2f(b1.x) + w2 * bf2f(c1.x));
  r1.y = f2bf(w0 * bf2f(a1.y) + w1 * bf2f(b1.y) + w2 * bf2f(c1.y));
  r1.z = f2bf(w0 * bf2f(a1.z) + w1 * bf2f(b1.z) + w2 * bf2f(c1.z));
  r1.w = f2bf(w0 * bf2f(a1.w) + w1 * bf2f(b1.w) + w2 * bf2f(c1.w));
  *(ushort4*)o = r0;
  *(ushort4*)(o + 4) = r1;
}

extern "C" void kernel_launch(void* const* d_in, const int* in_sizes, int n_in,
                              void* d_out, int out_size, void* d_ws, size_t ws_size,
                              hipStream_t stream) {
  const float* x   = (const float*)d_in[0];
  const float* wq  = (const float*)d_in[1];
  const float* wk  = (const float*)d_in[2];
  const float* wv  = (const float*)d_in[3];
  const float* wo  = (const float*)d_in[4];
  const float* ang = (const float*)d_in[5];
  const int* anch  = (const int*)d_in[6];

  char* ws = (char*)d_ws;
  const size_t SZ_SE = (size_t)S_LEN * HDTOT * sizeof(u16);  // 16 MB
  const size_t SZ_W  = (size_t)EMB * EMB * sizeof(u16);      // 8 MB
  u16* xb   = (u16*)(ws);
  u16* qb   = (u16*)(ws + SZ_SE);
  u16* kb   = (u16*)(ws + 2 * SZ_SE);
  u16* vb   = (u16*)(ws + 3 * SZ_SE);
  u16* vtb  = (u16*)(ws + 4 * SZ_SE);
  u16* attn = (u16*)(ws + 5 * SZ_SE);
  u16* wqT  = (u16*)(ws + 6 * SZ_SE);
  u16* wkT  = (u16*)(ws + 6 * SZ_SE + SZ_W);
  u16* wvT  = (u16*)(ws + 6 * SZ_SE + 2 * SZ_W);
  u16* woT  = (u16*)(ws + 6 * SZ_SE + 3 * SZ_W);

  // split-j partials alias regions that are DEAD by the time k_attn runs:
  //   pO0 <- vb   (vb consumed by k_transpose_v before k_attn)
  //   pO1 <- xb   (xb consumed by the three QKV GEMMs)
  //   pO2 <- wqT+wkT (consumed by QKV GEMMs; 16 MB contiguous)
  //   pM/pL <- wvT (consumed by the V GEMM; 8 MB)
  u16* pO0 = vb;
  u16* pO1 = xb;
  u16* pO2 = wqT;
  float* pM = (float*)wvT;
  float* pL = (float*)((char*)wvT + 4 * 1024 * 1024);

  k_convert_x<<<8192, 256, 0, stream>>>(x, xb);
  k_transpose_w<<<dim3(32, 32, 4), 256, 0, stream>>>(wq, wk, wv, wo, wqT, wkT, wvT, woT);
  k_gemm<true><<<dim3(16, 32), 256, 0, stream>>>(xb, wqT, qb, S_LEN, HDTOT, EMB);
  k_gemm<true><<<dim3(16, 32), 256, 0, stream>>>(xb, wkT, kb, S_LEN, HDTOT, EMB);
  k_gemm<true><<<dim3(16, 32), 256, 0, stream>>>(xb, wvT, vb, S_LEN, HDTOT, EMB);
  k_rope<<<16384, 256, 0, stream>>>(qb, kb, ang);
  k_transpose_v<<<dim3(32, 64), 256, 0, stream>>>(vb, vtb);
  k_attn<<<dim3(T_TILES, NH, NSPLIT), 256, 0, stream>>>(qb, kb, vtb, anch,
                                                        pO0, pO1, pO2, pM, pL);
  k_combine<<<4096, 256, 0, stream>>>(pO0, pO1, pO2, pM, pL, attn);
  k_gemm<false><<<dim3(16, 32), 256, 0, stream>>>(attn, woT, d_out, S_LEN, EMB, HDTOT);
}

// Round 3
// 640.821 us; speedup vs baseline: 1.0367x; 1.0367x over previous
//
#include <hip/hip_runtime.h>
#include <stdint.h>

typedef unsigned short u16;
typedef unsigned int u32;

#define S_LEN 4096
#define EMB 2048
#define NH 16
#define HD 128
#define HDTOT 2048
#define T_TILES 32
#define KANCH 8
#define SM_SCALE 0.088388347648318447f

typedef __bf16 bf16x8 __attribute__((ext_vector_type(8)));
typedef float f32x4 __attribute__((ext_vector_type(4)));

typedef const __attribute__((address_space(1))) u32 ga_u32;
typedef __attribute__((address_space(3))) u32 lds_u32;

__device__ __forceinline__ u16 f2bf(float f) {
  u32 b = __builtin_bit_cast(u32, f);
  b = (b + 0x7FFFu + ((b >> 16) & 1u)) >> 16;
  return (u16)b;
}
__device__ __forceinline__ float bf2f(u16 u) {
  return __builtin_bit_cast(float, ((u32)u) << 16);
}
__device__ __forceinline__ f32x4 mfma16(bf16x8 a, bf16x8 b, f32x4 c) {
  return __builtin_amdgcn_mfma_f32_16x16x32_bf16(a, b, c, 0, 0, 0);
}

// ---------------- x: fp32 -> bf16 ----------------
__global__ __launch_bounds__(256) void k_convert_x(const float* __restrict__ x,
                                                   u16* __restrict__ xb) {
  int i = (blockIdx.x * 256 + threadIdx.x) * 4;
  float4 v = *(const float4*)(x + i);
  ushort4 o;
  o.x = f2bf(v.x); o.y = f2bf(v.y); o.z = f2bf(v.z); o.w = f2bf(v.w);
  *(ushort4*)(xb + i) = o;
}

// ------- weights: [K=2048][N=2048] fp32 -> [N][K] bf16 (B^T for gemm) -------
__global__ __launch_bounds__(256) void k_transpose_w(
    const float* __restrict__ w0, const float* __restrict__ w1,
    const float* __restrict__ w2, const float* __restrict__ w3,
    u16* __restrict__ o0, u16* __restrict__ o1,
    u16* __restrict__ o2, u16* __restrict__ o3) {
  const float* w; u16* o;
  if (blockIdx.z == 0)      { w = w0; o = o0; }
  else if (blockIdx.z == 1) { w = w1; o = o1; }
  else if (blockIdx.z == 2) { w = w2; o = o2; }
  else                      { w = w3; o = o3; }
  __shared__ float tile[64][68];
  int n0 = blockIdx.x * 64, k0 = blockIdx.y * 64;
  int tid = threadIdx.x;
  int r = tid >> 4, cq = (tid & 15) << 2;
  for (int p = 0; p < 4; ++p) {
    float4 v = *(const float4*)(w + (size_t)(k0 + r + p * 16) * EMB + n0 + cq);
    tile[r + p * 16][cq + 0] = v.x;
    tile[r + p * 16][cq + 1] = v.y;
    tile[r + p * 16][cq + 2] = v.z;
    tile[r + p * 16][cq + 3] = v.w;
  }
  __syncthreads();
  for (int p = 0; p < 4; ++p) {
    int rn = r + p * 16;
    ushort4 u;
    u.x = f2bf(tile[cq + 0][rn]);
    u.y = f2bf(tile[cq + 1][rn]);
    u.z = f2bf(tile[cq + 2][rn]);
    u.w = f2bf(tile[cq + 3][rn]);
    *(ushort4*)(o + (size_t)(n0 + rn) * EMB + k0 + cq) = u;
  }
}

// ------- v: [S][HDTOT] bf16 -> vT [HDTOT][S] bf16 -------
__global__ __launch_bounds__(256) void k_transpose_v(const u16* __restrict__ v,
                                                     u16* __restrict__ vt) {
  __shared__ u16 tile[64][72];
  int n0 = blockIdx.x * 64, s0 = blockIdx.y * 64;
  int tid = threadIdx.x;
  int r = tid >> 4, cq = (tid & 15) << 2;
  for (int p = 0; p < 4; ++p) {
    ushort4 u = *(const ushort4*)(v + (size_t)(s0 + r + p * 16) * HDTOT + n0 + cq);
    tile[r + p * 16][cq + 0] = u.x;
    tile[r + p * 16][cq + 1] = u.y;
    tile[r + p * 16][cq + 2] = u.z;
    tile[r + p * 16][cq + 3] = u.w;
  }
  __syncthreads();
  for (int p = 0; p < 4; ++p) {
    int rn = r + p * 16;
    ushort4 o;
    o.x = tile[cq + 0][rn];
    o.y = tile[cq + 1][rn];
    o.z = tile[cq + 2][rn];
    o.w = tile[cq + 3][rn];
    *(ushort4*)(vt + (size_t)(n0 + rn) * S_LEN + s0 + cq) = o;
  }
}

// ------- m97-style bf16 GEMM: C[M][N] = A[M][K] * Bt[N][K]^T -------
template <bool BF16OUT>
__global__ __launch_bounds__(256) void k_gemm(const u16* __restrict__ A,
                                              const u16* __restrict__ Bt,
                                              void* __restrict__ Cv,
                                              int M, int N, int K) {
  __shared__ __align__(16) u16 As[128 * 32];
  __shared__ __align__(16) u16 Bs[128 * 32];
  const int tid = threadIdx.x;
  const int lane = tid & 63, wave = tid >> 6;
  const int quad = lane >> 4, l16 = lane & 15;
  const int m0 = blockIdx.y * 128, n0 = blockIdx.x * 128;
  const int wm = (wave >> 1) * 64, wn = (wave & 1) * 64;
  f32x4 acc[4][4] = {};

  const int flat0 = wave * 1024 + lane * 16;  // byte offset within 8KB tile
  for (int kt = 0; kt < K; kt += 32) {
    for (int half = 0; half < 2; ++half) {
      int flat = flat0 + half * 4096;
      int row = flat >> 6, colb = flat & 63;
      const char* ga = (const char*)A + ((size_t)(m0 + row) * K + kt) * 2 + colb;
      const char* gb = (const char*)Bt + ((size_t)(n0 + row) * K + kt) * 2 + colb;
      int loff = wave * 1024 + half * 4096;  // wave-uniform LDS byte offset
      __builtin_amdgcn_global_load_lds((ga_u32*)ga, (lds_u32*)((char*)As + loff), 16, 0, 0);
      __builtin_amdgcn_global_load_lds((ga_u32*)gb, (lds_u32*)((char*)Bs + loff), 16, 0, 0);
    }
    __syncthreads();
    bf16x8 af[4], bfr[4];
    for (int mt = 0; mt < 4; ++mt)
      af[mt] = *(const bf16x8*)(As + (wm + mt * 16 + l16) * 32 + quad * 8);
    for (int nt = 0; nt < 4; ++nt)
      bfr[nt] = *(const bf16x8*)(Bs + (wn + nt * 16 + l16) * 32 + quad * 8);
    for (int mt = 0; mt < 4; ++mt)
      for (int nt = 0; nt < 4; ++nt)
        acc[mt][nt] = mfma16(af[mt], bfr[nt], acc[mt][nt]);
    __syncthreads();
  }
  for (int mt = 0; mt < 4; ++mt) {
    int row = m0 + wm + mt * 16 + quad * 4;
    for (int nt = 0; nt < 4; ++nt) {
      int col = n0 + wn + nt * 16 + l16;
      for (int r = 0; r < 4; ++r) {
        if (BF16OUT)
          ((u16*)Cv)[(size_t)(row + r) * N + col] = f2bf(acc[mt][nt][r]);
        else
          ((float*)Cv)[(size_t)(row + r) * N + col] = acc[mt][nt][r];
      }
    }
  }
}

// ------- RoPE (half-split) applied in-place to q and k -------
__global__ __launch_bounds__(256) void k_rope(u16* __restrict__ q, u16* __restrict__ k,
                                              const float* __restrict__ ang) {
  int gid = blockIdx.x * 256 + threadIdx.x;  // S*NH*64
  int s = gid >> 10;
  int h = (gid >> 6) & (NH - 1);
  int d = gid & 63;
  float a = ang[s * 64 + d];
  float sn, cs;
  __sincosf(a, &sn, &cs);
  size_t base = (size_t)s * HDTOT + h * HD + d;
  float q1 = bf2f(q[base]), q2 = bf2f(q[base + 64]);
  q[base] = f2bf(q1 * cs - q2 * sn);
  q[base + 64] = f2bf(q2 * cs + q1 * sn);
  float k1 = bf2f(k[base]), k2 = bf2f(k[base + 64]);
  k[base] = f2bf(k1 * cs - k2 * sn);
  k[base + 64] = f2bf(k2 * cs + k1 * sn);
}

// ------- swizzled LDS fragment read -------
__device__ __forceinline__ bf16x8 ldsfrag(const u16* __restrict__ sbuf, int r, int cb) {
  return *(const bf16x8*)(sbuf + r * 128 + (((cb ^ (r & 15)) << 3)));
}

// ------- block-sparse flash attention: one block per (t, h) ----------------
// Register-prefetch pipeline: while computing on tile j in LDS, tile j+1's
// K and V are in flight into registers (global load latency hidden behind
// QK + softmax + PV, ~3k cyc). VGPR peak ~240; __launch_bounds__(256,2)
// caps at 256 so LDS (64KB -> 2 blocks/CU) stays the occupancy limit.
__global__ __launch_bounds__(256, 2) void k_attn(const u16* __restrict__ q,
                                                 const u16* __restrict__ k,
                                                 const u16* __restrict__ vt,
                                                 const int* __restrict__ anch,
                                                 u16* __restrict__ out) {
  __shared__ __align__(16) u16 bufK[128 * 128];  // Q -> K_j -> P overlay
  __shared__ __align__(16) u16 bufV[128 * 128];  // V_j^T
  __shared__ int s_tj[KANCH + 1];
  __shared__ int s_nv;
  const int t = blockIdx.x, h = blockIdx.y;
  const int tid = threadIdx.x;
  const int lane = tid & 63, wave = tid >> 6;
  const int quad = lane >> 4, l16 = lane & 15;
  const int srow = tid >> 4;          // staging row within 16-row group
  const int scol = (tid & 15) << 3;   // staging col (8 elems per thread)
  const int scswz_base = scol >> 3;

  // valid tile list (uniform), computed once into LDS
  if (tid == 0) {
    int nv = 0;
    for (int j = 0; j < KANCH; ++j) {
      int tj = anch[((h * T_TILES) + t) * KANCH + j];
      if (tj <= t) s_tj[nv++] = tj;  // tj > t: fully future-masked, skip
    }
    s_tj[nv++] = t;  // local/diagonal tile, always valid
    s_nv = nv;
  }

  // stage Q tile (via regs), pull A-frags to registers
  uint4 regK[8], regV[8];
  {
    const u16* g = q + (size_t)(t * 128) * HDTOT + h * HD;
#pragma unroll
    for (int p = 0; p < 8; ++p)
      regK[p] = *(const uint4*)(g + (size_t)(srow + p * 16) * HDTOT + scol);
#pragma unroll
    for (int p = 0; p < 8; ++p) {
      int r = srow + p * 16;
      *(uint4*)(bufK + r * 128 + (((scswz_base ^ (r & 15)) << 3))) = regK[p];
    }
  }
  __syncthreads();
  bf16x8 qf[2][4];
#pragma unroll
  for (int mt = 0; mt < 2; ++mt)
#pragma unroll
    for (int ks = 0; ks < 4; ++ks)
      qf[mt][ks] = ldsfrag(bufK, wave * 32 + mt * 16 + l16, ks * 4 + quad);

  const int nv = s_nv;
  const u16* kh = k + h * HD;
  const u16* vh = vt + (size_t)(h * HD) * S_LEN;

  // issue first tile's loads (in flight across the next barrier)
  {
    const int tj0 = s_tj[0];
    const u16* gk = kh + (size_t)(tj0 * 128) * HDTOT;
    const u16* gv = vh + tj0 * 128;
#pragma unroll
    for (int p = 0; p < 8; ++p)
      regK[p] = *(const uint4*)(gk + (size_t)(srow + p * 16) * HDTOT + scol);
#pragma unroll
    for (int p = 0; p < 8; ++p)
      regV[p] = *(const uint4*)(gv + (size_t)(srow + p * 16) * S_LEN + scol);
  }
  __syncthreads();  // all waves done reading bufK (Q frags)

  f32x4 oacc[2][8] = {};
  float mrow[2][4], lrow[2][4];
#pragma unroll
  for (int mt = 0; mt < 2; ++mt)
#pragma unroll
    for (int r = 0; r < 4; ++r) { mrow[mt][r] = -1e30f; lrow[mt][r] = 0.f; }

  for (int i = 0; i < nv; ++i) {
    const int tj = s_tj[i];
    const bool diag = (tj == t);

    // drain prefetch regs into LDS
#pragma unroll
    for (int p = 0; p < 8; ++p) {
      int r = srow + p * 16;
      int cs = ((scswz_base ^ (r & 15)) << 3);
      *(uint4*)(bufK + r * 128 + cs) = regK[p];
      *(uint4*)(bufV + r * 128 + cs) = regV[p];
    }
    __syncthreads();

    // prefetch next tile into regs (hidden behind QK/softmax/PV)
    if (i + 1 < nv) {
      const int tjn = s_tj[i + 1];
      const u16* gk = kh + (size_t)(tjn * 128) * HDTOT;
      const u16* gv = vh + tjn * 128;
#pragma unroll
      for (int p = 0; p < 8; ++p)
        regK[p] = *(const uint4*)(gk + (size_t)(srow + p * 16) * HDTOT + scol);
#pragma unroll
      for (int p = 0; p < 8; ++p)
        regV[p] = *(const uint4*)(gv + (size_t)(srow + p * 16) * S_LEN + scol);
    }

    // S = Q K^T  (wave owns 32 q-rows x 128 keys)
    f32x4 sacc[2][8] = {};
#pragma unroll
    for (int ks = 0; ks < 4; ++ks)
#pragma unroll
      for (int nt = 0; nt < 8; ++nt) {
        bf16x8 bk = ldsfrag(bufK, nt * 16 + l16, ks * 4 + quad);
        sacc[0][nt] = mfma16(qf[0][ks], bk, sacc[0][nt]);
        sacc[1][nt] = mfma16(qf[1][ks], bk, sacc[1][nt]);
      }
    __syncthreads();  // all waves done reading K; bufK free for P overlay

#pragma unroll
    for (int mt = 0; mt < 2; ++mt) {
      float rmax[4] = {-1e30f, -1e30f, -1e30f, -1e30f};
#pragma unroll
      for (int nt = 0; nt < 8; ++nt) {
        f32x4 s4 = sacc[mt][nt];
#pragma unroll
        for (int r = 0; r < 4; ++r) {
          float sv = s4[r] * SM_SCALE;
          if (diag && (nt * 16 + l16 > wave * 32 + mt * 16 + quad * 4 + r)) sv = -1e30f;
          s4[r] = sv;
          rmax[r] = fmaxf(rmax[r], sv);
        }
        sacc[mt][nt] = s4;
      }
      float alpha[4];
#pragma unroll
      for (int r = 0; r < 4; ++r) {
        float rm = rmax[r];
        rm = fmaxf(rm, __shfl_xor(rm, 1));
        rm = fmaxf(rm, __shfl_xor(rm, 2));
        rm = fmaxf(rm, __shfl_xor(rm, 4));
        rm = fmaxf(rm, __shfl_xor(rm, 8));
        float mnew = fmaxf(mrow[mt][r], rm);
        alpha[r] = __expf(mrow[mt][r] - mnew);
        mrow[mt][r] = mnew;
      }
      float rsum[4] = {0.f, 0.f, 0.f, 0.f};
#pragma unroll
      for (int nt = 0; nt < 8; ++nt) {
        f32x4 s4 = sacc[mt][nt];
#pragma unroll
        for (int r = 0; r < 4; ++r) {
          float p = __expf(s4[r] - mrow[mt][r]);
          s4[r] = p;
          rsum[r] += p;
        }
        sacc[mt][nt] = s4;
      }
#pragma unroll
      for (int r = 0; r < 4; ++r) {
        float rs = rsum[r];
        rs += __shfl_xor(rs, 1);
        rs += __shfl_xor(rs, 2);
        rs += __shfl_xor(rs, 4);
        rs += __shfl_xor(rs, 8);
        lrow[mt][r] = lrow[mt][r] * alpha[r] + rs;
      }
      // rescale O and write P (bf16) into bufK overlay
#pragma unroll
      for (int nt = 0; nt < 8; ++nt) {
        f32x4 o4 = oacc[mt][nt];
        f32x4 s4 = sacc[mt][nt];
#pragma unroll
        for (int r = 0; r < 4; ++r) {
          o4[r] *= alpha[r];
          int qrow = wave * 32 + mt * 16 + quad * 4 + r;
          int c = nt * 16 + l16;
          bufK[qrow * 128 + ((((c >> 3) ^ (qrow & 15)) << 3)) + (c & 7)] = f2bf(s4[r]);
        }
        oacc[mt][nt] = o4;
      }
    }
    __syncthreads();  // P visible in A-layout order

    // O += P V  (A-frags from P overlay, B-frags from V^T)
#pragma unroll
    for (int ks = 0; ks < 4; ++ks) {
      bf16x8 pa0 = ldsfrag(bufK, wave * 32 + l16, ks * 4 + quad);
      bf16x8 pa1 = ldsfrag(bufK, wave * 32 + 16 + l16, ks * 4 + quad);
#pragma unroll
      for (int nt = 0; nt < 8; ++nt) {
        bf16x8 bv = ldsfrag(bufV, nt * 16 + l16, ks * 4 + quad);
        oacc[0][nt] = mfma16(pa0, bv, oacc[0][nt]);
        oacc[1][nt] = mfma16(pa1, bv, oacc[1][nt]);
      }
    }
    __syncthreads();  // done reading bufK/bufV before next drain
  }

#pragma unroll
  for (int mt = 0; mt < 2; ++mt)
#pragma unroll
    for (int r = 0; r < 4; ++r) {
      float inv = 1.0f / lrow[mt][r];
      size_t srow_o = (size_t)(t * 128 + wave * 32 + mt * 16 + quad * 4 + r);
#pragma unroll
      for (int nt = 0; nt < 8; ++nt)
        out[srow_o * HDTOT + h * HD + nt * 16 + l16] = f2bf(oacc[mt][nt][r] * inv);
    }
}

extern "C" void kernel_launch(void* const* d_in, const int* in_sizes, int n_in,
                              void* d_out, int out_size, void* d_ws, size_t ws_size,
                              hipStream_t stream) {
  const float* x   = (const float*)d_in[0];
  const float* wq  = (const float*)d_in[1];
  const float* wk  = (const float*)d_in[2];
  const float* wv  = (const float*)d_in[3];
  const float* wo  = (const float*)d_in[4];
  const float* ang = (const float*)d_in[5];
  const int* anch  = (const int*)d_in[6];

  char* ws = (char*)d_ws;
  const size_t SZ_SE = (size_t)S_LEN * HDTOT * sizeof(u16);  // 16 MB
  const size_t SZ_W  = (size_t)EMB * EMB * sizeof(u16);      // 8 MB
  u16* xb   = (u16*)(ws);
  u16* qb   = (u16*)(ws + SZ_SE);
  u16* kb   = (u16*)(ws + 2 * SZ_SE);
  u16* vb   = (u16*)(ws + 3 * SZ_SE);
  u16* vtb  = (u16*)(ws + 4 * SZ_SE);
  u16* attn = (u16*)(ws + 5 * SZ_SE);
  u16* wqT  = (u16*)(ws + 6 * SZ_SE);
  u16* wkT  = (u16*)(ws + 6 * SZ_SE + SZ_W);
  u16* wvT  = (u16*)(ws + 6 * SZ_SE + 2 * SZ_W);
  u16* woT  = (u16*)(ws + 6 * SZ_SE + 3 * SZ_W);

  k_convert_x<<<8192, 256, 0, stream>>>(x, xb);
  k_transpose_w<<<dim3(32, 32, 4), 256, 0, stream>>>(wq, wk, wv, wo, wqT, wkT, wvT, woT);
  k_gemm<true><<<dim3(16, 32), 256, 0, stream>>>(xb, wqT, qb, S_LEN, HDTOT, EMB);
  k_gemm<true><<<dim3(16, 32), 256, 0, stream>>>(xb, wkT, kb, S_LEN, HDTOT, EMB);
  k_gemm<true><<<dim3(16, 32), 256, 0, stream>>>(xb, wvT, vb, S_LEN, HDTOT, EMB);
  k_rope<<<16384, 256, 0, stream>>>(qb, kb, ang);
  k_transpose_v<<<dim3(32, 64), 256, 0, stream>>>(vb, vtb);
  k_attn<<<dim3(T_TILES, NH), 256, 0, stream>>>(qb, kb, vtb, anch, attn);
  k_gemm<false><<<dim3(16, 32), 256, 0, stream>>>(attn, woT, d_out, S_LEN, EMB, HDTOT);
}

// Round 4
// 493.025 us; speedup vs baseline: 1.3475x; 1.2998x over previous
//
#include <hip/hip_runtime.h>
#include <stdint.h>

typedef unsigned short u16;
typedef unsigned int u32;

#define S_LEN 4096
#define EMB 2048
#define NH 16
#define HD 128
#define HDTOT 2048
#define T_TILES 32
#define KANCH 8
#define SM_SCALE 0.088388347648318447f

typedef __bf16 bf16x8 __attribute__((ext_vector_type(8)));
typedef float f32x4 __attribute__((ext_vector_type(4)));

typedef const __attribute__((address_space(1))) u32 ga_u32;
typedef __attribute__((address_space(3))) u32 lds_u32;

__device__ __forceinline__ u16 f2bf(float f) {
  u32 b = __builtin_bit_cast(u32, f);
  b = (b + 0x7FFFu + ((b >> 16) & 1u)) >> 16;
  return (u16)b;
}
__device__ __forceinline__ float bf2f(u16 u) {
  return __builtin_bit_cast(float, ((u32)u) << 16);
}
__device__ __forceinline__ f32x4 mfma16(bf16x8 a, bf16x8 b, f32x4 c) {
  return __builtin_amdgcn_mfma_f32_16x16x32_bf16(a, b, c, 0, 0, 0);
}

// ---------------- x: fp32 -> bf16 ----------------
__global__ __launch_bounds__(256) void k_convert_x(const float* __restrict__ x,
                                                   u16* __restrict__ xb) {
  int i = (blockIdx.x * 256 + threadIdx.x) * 4;
  float4 v = *(const float4*)(x + i);
  ushort4 o;
  o.x = f2bf(v.x); o.y = f2bf(v.y); o.z = f2bf(v.z); o.w = f2bf(v.w);
  *(ushort4*)(xb + i) = o;
}

// ------- weights: [K=2048][N=2048] fp32 -> [N][K] bf16 (B^T for gemm) -------
__global__ __launch_bounds__(256) void k_transpose_w(
    const float* __restrict__ w0, const float* __restrict__ w1,
    const float* __restrict__ w2, const float* __restrict__ w3,
    u16* __restrict__ o0, u16* __restrict__ o1,
    u16* __restrict__ o2, u16* __restrict__ o3) {
  const float* w; u16* o;
  if (blockIdx.z == 0)      { w = w0; o = o0; }
  else if (blockIdx.z == 1) { w = w1; o = o1; }
  else if (blockIdx.z == 2) { w = w2; o = o2; }
  else                      { w = w3; o = o3; }
  __shared__ float tile[64][68];
  int n0 = blockIdx.x * 64, k0 = blockIdx.y * 64;
  int tid = threadIdx.x;
  int r = tid >> 4, cq = (tid & 15) << 2;
  for (int p = 0; p < 4; ++p) {
    float4 v = *(const float4*)(w + (size_t)(k0 + r + p * 16) * EMB + n0 + cq);
    tile[r + p * 16][cq + 0] = v.x;
    tile[r + p * 16][cq + 1] = v.y;
    tile[r + p * 16][cq + 2] = v.z;
    tile[r + p * 16][cq + 3] = v.w;
  }
  __syncthreads();
  for (int p = 0; p < 4; ++p) {
    int rn = r + p * 16;
    ushort4 u;
    u.x = f2bf(tile[cq + 0][rn]);
    u.y = f2bf(tile[cq + 1][rn]);
    u.z = f2bf(tile[cq + 2][rn]);
    u.w = f2bf(tile[cq + 3][rn]);
    *(ushort4*)(o + (size_t)(n0 + rn) * EMB + k0 + cq) = u;
  }
}

// ------- v: [S][HDTOT] bf16 -> vT [HDTOT][S] bf16 -------
__global__ __launch_bounds__(256) void k_transpose_v(const u16* __restrict__ v,
                                                     u16* __restrict__ vt) {
  __shared__ u16 tile[64][72];
  int n0 = blockIdx.x * 64, s0 = blockIdx.y * 64;
  int tid = threadIdx.x;
  int r = tid >> 4, cq = (tid & 15) << 2;
  for (int p = 0; p < 4; ++p) {
    ushort4 u = *(const ushort4*)(v + (size_t)(s0 + r + p * 16) * HDTOT + n0 + cq);
    tile[r + p * 16][cq + 0] = u.x;
    tile[r + p * 16][cq + 1] = u.y;
    tile[r + p * 16][cq + 2] = u.z;
    tile[r + p * 16][cq + 3] = u.w;
  }
  __syncthreads();
  for (int p = 0; p < 4; ++p) {
    int rn = r + p * 16;
    ushort4 o;
    o.x = tile[cq + 0][rn];
    o.y = tile[cq + 1][rn];
    o.z = tile[cq + 2][rn];
    o.w = tile[cq + 3][rn];
    *(ushort4*)(vt + (size_t)(n0 + rn) * S_LEN + s0 + cq) = o;
  }
}

// ------- m97-style bf16 GEMM: C[M][N] = A[M][K] * Bt[N][K]^T -------
template <bool BF16OUT>
__global__ __launch_bounds__(256) void k_gemm(const u16* __restrict__ A,
                                              const u16* __restrict__ Bt,
                                              void* __restrict__ Cv,
                                              int M, int N, int K) {
  __shared__ __align__(16) u16 As[128 * 32];
  __shared__ __align__(16) u16 Bs[128 * 32];
  const int tid = threadIdx.x;
  const int lane = tid & 63, wave = tid >> 6;
  const int quad = lane >> 4, l16 = lane & 15;
  const int m0 = blockIdx.y * 128, n0 = blockIdx.x * 128;
  const int wm = (wave >> 1) * 64, wn = (wave & 1) * 64;
  f32x4 acc[4][4] = {};

  const int flat0 = wave * 1024 + lane * 16;  // byte offset within 8KB tile
  for (int kt = 0; kt < K; kt += 32) {
    for (int half = 0; half < 2; ++half) {
      int flat = flat0 + half * 4096;
      int row = flat >> 6, colb = flat & 63;
      const char* ga = (const char*)A + ((size_t)(m0 + row) * K + kt) * 2 + colb;
      const char* gb = (const char*)Bt + ((size_t)(n0 + row) * K + kt) * 2 + colb;
      int loff = wave * 1024 + half * 4096;  // wave-uniform LDS byte offset
      __builtin_amdgcn_global_load_lds((ga_u32*)ga, (lds_u32*)((char*)As + loff), 16, 0, 0);
      __builtin_amdgcn_global_load_lds((ga_u32*)gb, (lds_u32*)((char*)Bs + loff), 16, 0, 0);
    }
    __syncthreads();
    bf16x8 af[4], bfr[4];
    for (int mt = 0; mt < 4; ++mt)
      af[mt] = *(const bf16x8*)(As + (wm + mt * 16 + l16) * 32 + quad * 8);
    for (int nt = 0; nt < 4; ++nt)
      bfr[nt] = *(const bf16x8*)(Bs + (wn + nt * 16 + l16) * 32 + quad * 8);
    for (int mt = 0; mt < 4; ++mt)
      for (int nt = 0; nt < 4; ++nt)
        acc[mt][nt] = mfma16(af[mt], bfr[nt], acc[mt][nt]);
    __syncthreads();
  }
  for (int mt = 0; mt < 4; ++mt) {
    int row = m0 + wm + mt * 16 + quad * 4;
    for (int nt = 0; nt < 4; ++nt) {
      int col = n0 + wn + nt * 16 + l16;
      for (int r = 0; r < 4; ++r) {
        if (BF16OUT)
          ((u16*)Cv)[(size_t)(row + r) * N + col] = f2bf(acc[mt][nt][r]);
        else
          ((float*)Cv)[(size_t)(row + r) * N + col] = acc[mt][nt][r];
      }
    }
  }
}

// ------- RoPE (half-split) applied in-place to q and k -------
__global__ __launch_bounds__(256) void k_rope(u16* __restrict__ q, u16* __restrict__ k,
                                              const float* __restrict__ ang) {
  int gid = blockIdx.x * 256 + threadIdx.x;  // S*NH*64
  int s = gid >> 10;
  int h = (gid >> 6) & (NH - 1);
  int d = gid & 63;
  float a = ang[s * 64 + d];
  float sn, cs;
  __sincosf(a, &sn, &cs);
  size_t base = (size_t)s * HDTOT + h * HD + d;
  float q1 = bf2f(q[base]), q2 = bf2f(q[base + 64]);
  q[base] = f2bf(q1 * cs - q2 * sn);
  q[base + 64] = f2bf(q2 * cs + q1 * sn);
  float k1 = bf2f(k[base]), k2 = bf2f(k[base + 64]);
  k[base] = f2bf(k1 * cs - k2 * sn);
  k[base + 64] = f2bf(k2 * cs + k1 * sn);
}

// ------- swizzled LDS fragment read (128-col bf16 tile, XOR-swizzled) -------
__device__ __forceinline__ bf16x8 ldsfrag(const u16* __restrict__ sbuf, int r, int cb) {
  return *(const bf16x8*)(sbuf + r * 128 + (((cb ^ (r & 15)) << 3)));
}

// ------- block-sparse flash attention: one block per (t, h) ----------------
// Restructured K-loop: async global_load_lds double-buffered K/V (128 KB LDS,
// 1 block/CU), ONE barrier per tile-iteration, S computed TRANSPOSED
// (S^T = K·Q^T) so softmax reduces in-lane and P converts to PV A-frags via
// register shfl-transpose — no P LDS round-trip, no spillable reg staging.
__global__ __launch_bounds__(256, 1) void k_attn(const u16* __restrict__ q,
                                                 const u16* __restrict__ k,
                                                 const u16* __restrict__ vt,
                                                 const int* __restrict__ anch,
                                                 u16* __restrict__ out) {
  __shared__ __align__(16) u16 bufK[2][128 * 128];
  __shared__ __align__(16) u16 bufV[2][128 * 128];
  __shared__ int s_tj[KANCH + 1];
  __shared__ int s_nv;
  const int t = T_TILES - 1 - blockIdx.x;  // heavy (high-t) blocks first
  const int h = blockIdx.y;
  const int tid = threadIdx.x;
  const int lane = tid & 63, wave = tid >> 6;
  const int quad = lane >> 4, l16 = lane & 15;
  const int wq0 = wave * 32;

  // Per-lane byte offsets within a 128x128 bf16 tile for this wave's 8 chunks.
  // Chunk ch = wave*8+p covers rows ch*4..ch*4+3 (1 KB LDS = lane*16 linear);
  // the XOR swizzle is folded into the GLOBAL column (within-row permute, so
  // coalescing is unchanged and LDS dest stays the HW-required linear form).
  int offK[8], offV[8];
#pragma unroll
  for (int p = 0; p < 8; ++p) {
    int ch = wave * 8 + p;
    int row = ch * 4 + (lane >> 4);
    int colsw = ((lane & 15) ^ (row & 15)) << 3;
    offK[p] = (row * HDTOT + colsw) * 2;  // K/Q pitch = HDTOT elems
    offV[p] = (row * S_LEN + colsw) * 2;  // V^T pitch = S_LEN elems
  }

  if (tid == 0) {
    int nv = 0;
    for (int j = 0; j < KANCH; ++j) {
      int tj = anch[((h * T_TILES) + t) * KANCH + j];
      if (tj <= t) s_tj[nv++] = tj;  // tj > t: fully future-masked, skip
    }
    s_tj[nv++] = t;  // local/diagonal tile
    s_nv = nv;
  }

  // stage Q (tile t) into bufV[1] (free until iteration 1's V prefetch)
  {
    const char* gq = (const char*)(q + (size_t)(t * 128) * HDTOT + h * HD);
    char* lq = (char*)bufV[1] + wave * 8192;
#pragma unroll
    for (int p = 0; p < 8; ++p)
      __builtin_amdgcn_global_load_lds((ga_u32*)(gq + offK[p]),
                                       (lds_u32*)(lq + p * 1024), 16, 0, 0);
  }
  __syncthreads();  // Q arrived (vmcnt drain at barrier), s_tj visible

  bf16x8 qf[2][4];  // Q B-frags: lane n=l16 -> qrow wq0+mt*16+l16, k=d
#pragma unroll
  for (int mt = 0; mt < 2; ++mt)
#pragma unroll
    for (int ks = 0; ks < 4; ++ks)
      qf[mt][ks] = ldsfrag(bufV[1], wq0 + mt * 16 + l16, ks * 4 + quad);

  const int nv = s_nv;
  const char* kh = (const char*)(k + h * HD);
  const char* vh = (const char*)(vt + (size_t)(h * HD) * S_LEN);

  // issue tile 0 loads (drained at first loop barrier)
  {
    int tj0 = s_tj[0];
    const char* gk = kh + (size_t)(tj0 * 128) * (HDTOT * 2);
    const char* gv = vh + (size_t)(tj0 * 128) * 2;
    char* lk = (char*)bufK[0] + wave * 8192;
    char* lv = (char*)bufV[0] + wave * 8192;
#pragma unroll
    for (int p = 0; p < 8; ++p) {
      __builtin_amdgcn_global_load_lds((ga_u32*)(gk + offK[p]),
                                       (lds_u32*)(lk + p * 1024), 16, 0, 0);
      __builtin_amdgcn_global_load_lds((ga_u32*)(gv + offV[p]),
                                       (lds_u32*)(lv + p * 1024), 16, 0, 0);
    }
  }

  f32x4 oacc[2][8] = {};
  float m_st[2] = {-1e30f, -1e30f}, l_st[2] = {0.f, 0.f};

  for (int i = 0; i < nv; ++i) {
    const int par = i & 1;
    const u16* K_c = bufK[par];
    const u16* V_c = bufV[par];
    const int tj = s_tj[i];
    const bool diag = (tj == t);

    __syncthreads();  // drains tile-i loads; WAR-protects buffer 1-par

    // prefetch tile i+1 (in flight for the whole compute phase below)
    if (i + 1 < nv) {
      int tjn = s_tj[i + 1];
      const char* gk = kh + (size_t)(tjn * 128) * (HDTOT * 2);
      const char* gv = vh + (size_t)(tjn * 128) * 2;
      char* lk = (char*)bufK[1 - par] + wave * 8192;
      char* lv = (char*)bufV[1 - par] + wave * 8192;
#pragma unroll
      for (int p = 0; p < 8; ++p) {
        __builtin_amdgcn_global_load_lds((ga_u32*)(gk + offK[p]),
                                         (lds_u32*)(lk + p * 1024), 16, 0, 0);
        __builtin_amdgcn_global_load_lds((ga_u32*)(gv + offV[p]),
                                         (lds_u32*)(lv + p * 1024), 16, 0, 0);
      }
    }

    // S^T = K·Q^T : sacc[mt][a][r] = S[qrow=wq0+mt*16+l16][key=a*16+quad*4+r]
    f32x4 sacc[2][8] = {};
#pragma unroll
    for (int ks = 0; ks < 4; ++ks)
#pragma unroll
      for (int a = 0; a < 8; ++a) {
        bf16x8 kf = ldsfrag(K_c, a * 16 + l16, ks * 4 + quad);
        sacc[0][a] = mfma16(kf, qf[0][ks], sacc[0][a]);
        sacc[1][a] = mfma16(kf, qf[1][ks], sacc[1][a]);
      }

    // online softmax: lane holds 32 keys per qrow (8 tiles x 4 consecutive)
    u32 pl[2][8], ph[2][8];
    float alpha[2];
#pragma unroll
    for (int mt = 0; mt < 2; ++mt) {
      const int qr = wq0 + mt * 16 + l16;
      float rmax = -1e30f;
#pragma unroll
      for (int a = 0; a < 8; ++a) {
        f32x4 s4 = sacc[mt][a];
#pragma unroll
        for (int r = 0; r < 4; ++r) {
          float sv = s4[r] * SM_SCALE;
          if (diag && (a * 16 + quad * 4 + r > qr)) sv = -1e30f;
          s4[r] = sv;
          rmax = fmaxf(rmax, sv);
        }
        sacc[mt][a] = s4;
      }
      rmax = fmaxf(rmax, __shfl_xor(rmax, 16));
      rmax = fmaxf(rmax, __shfl_xor(rmax, 32));
      float mnew = fmaxf(m_st[mt], rmax);
      alpha[mt] = __expf(m_st[mt] - mnew);
      m_st[mt] = mnew;
      float rsum = 0.f;
#pragma unroll
      for (int a = 0; a < 8; ++a) {
        f32x4 s4 = sacc[mt][a];
        float p0 = __expf(s4[0] - mnew);
        float p1 = __expf(s4[1] - mnew);
        float p2 = __expf(s4[2] - mnew);
        float p3 = __expf(s4[3] - mnew);
        rsum += (p0 + p1) + (p2 + p3);
        // pack pairs to bf16 (round-half-up via +0x8000, pick high halves)
        pl[mt][a] = __builtin_amdgcn_perm(__builtin_bit_cast(u32, p1) + 0x8000u,
                                          __builtin_bit_cast(u32, p0) + 0x8000u,
                                          0x07060302u);
        ph[mt][a] = __builtin_amdgcn_perm(__builtin_bit_cast(u32, p3) + 0x8000u,
                                          __builtin_bit_cast(u32, p2) + 0x8000u,
                                          0x07060302u);
      }
      rsum += __shfl_xor(rsum, 16);
      rsum += __shfl_xor(rsum, 32);
      l_st[mt] = l_st[mt] * alpha[mt] + rsum;
    }

    // rescale O (O rows are quad*4+r; alpha lives at lane l16 == row)
#pragma unroll
    for (int mt = 0; mt < 2; ++mt) {
      f32x4 av;
#pragma unroll
      for (int r = 0; r < 4; ++r)
        av[r] = __shfl(alpha[mt], (lane & 48) | (quad * 4 + r));
#pragma unroll
      for (int nt = 0; nt < 8; ++nt) {
        f32x4 o4 = oacc[mt][nt];
        o4[0] *= av[0]; o4[1] *= av[1]; o4[2] *= av[2]; o4[3] *= av[3];
        oacc[mt][nt] = o4;
      }
    }

    // O += P·V : A-frags via register shfl-transpose of packed P
    const int srcA = ((quad & 1) << 5) + l16;  // source lane (quads 0/2 pair)
    const int srcB = srcA + 16;
    const int hi = quad >> 1;
#pragma unroll
    for (int c = 0; c < 4; ++c) {
      bf16x8 pa[2];
#pragma unroll
      for (int mt = 0; mt < 2; ++mt) {
        u32 x0 = __shfl(pl[mt][2 * c], srcA), x1 = __shfl(ph[mt][2 * c], srcA);
        u32 x2 = __shfl(pl[mt][2 * c], srcB), x3 = __shfl(ph[mt][2 * c], srcB);
        u32 y0 = __shfl(pl[mt][2 * c + 1], srcA), y1 = __shfl(ph[mt][2 * c + 1], srcA);
        u32 y2 = __shfl(pl[mt][2 * c + 1], srcB), y3 = __shfl(ph[mt][2 * c + 1], srcB);
        uint4 w;
        w.x = hi ? y0 : x0;
        w.y = hi ? y1 : x1;
        w.z = hi ? y2 : x2;
        w.w = hi ? y3 : x3;
        pa[mt] = __builtin_bit_cast(bf16x8, w);
      }
#pragma unroll
      for (int nt = 0; nt < 8; ++nt) {
        bf16x8 vf = ldsfrag(V_c, nt * 16 + l16, c * 4 + quad);
        oacc[0][nt] = mfma16(pa[0], vf, oacc[0][nt]);
        oacc[1][nt] = mfma16(pa[1], vf, oacc[1][nt]);
      }
    }
  }

  // epilogue: normalize rows (1/l via shfl to O-row lanes) and store
#pragma unroll
  for (int mt = 0; mt < 2; ++mt) {
    float linv = 1.0f / l_st[mt];
    f32x4 iv;
#pragma unroll
    for (int r = 0; r < 4; ++r)
      iv[r] = __shfl(linv, (lane & 48) | (quad * 4 + r));
#pragma unroll
    for (int r = 0; r < 4; ++r) {
      size_t srow_o = (size_t)(t * 128 + wq0 + mt * 16 + quad * 4 + r);
#pragma unroll
      for (int nt = 0; nt < 8; ++nt)
        out[srow_o * HDTOT + h * HD + nt * 16 + l16] = f2bf(oacc[mt][nt][r] * iv[r]);
    }
  }
}

extern "C" void kernel_launch(void* const* d_in, const int* in_sizes, int n_in,
                              void* d_out, int out_size, void* d_ws, size_t ws_size,
                              hipStream_t stream) {
  const float* x   = (const float*)d_in[0];
  const float* wq  = (const float*)d_in[1];
  const float* wk  = (const float*)d_in[2];
  const float* wv  = (const float*)d_in[3];
  const float* wo  = (const float*)d_in[4];
  const float* ang = (const float*)d_in[5];
  const int* anch  = (const int*)d_in[6];

  char* ws = (char*)d_ws;
  const size_t SZ_SE = (size_t)S_LEN * HDTOT * sizeof(u16);  // 16 MB
  const size_t SZ_W  = (size_t)EMB * EMB * sizeof(u16);      // 8 MB
  u16* xb   = (u16*)(ws);
  u16* qb   = (u16*)(ws + SZ_SE);
  u16* kb   = (u16*)(ws + 2 * SZ_SE);
  u16* vb   = (u16*)(ws + 3 * SZ_SE);
  u16* vtb  = (u16*)(ws + 4 * SZ_SE);
  u16* attn = (u16*)(ws + 5 * SZ_SE);
  u16* wqT  = (u16*)(ws + 6 * SZ_SE);
  u16* wkT  = (u16*)(ws + 6 * SZ_SE + SZ_W);
  u16* wvT  = (u16*)(ws + 6 * SZ_SE + 2 * SZ_W);
  u16* woT  = (u16*)(ws + 6 * SZ_SE + 3 * SZ_W);

  k_convert_x<<<8192, 256, 0, stream>>>(x, xb);
  k_transpose_w<<<dim3(32, 32, 4), 256, 0, stream>>>(wq, wk, wv, wo, wqT, wkT, wvT, woT);
  k_gemm<true><<<dim3(16, 32), 256, 0, stream>>>(xb, wqT, qb, S_LEN, HDTOT, EMB);
  k_gemm<true><<<dim3(16, 32), 256, 0, stream>>>(xb, wkT, kb, S_LEN, HDTOT, EMB);
  k_gemm<true><<<dim3(16, 32), 256, 0, stream>>>(xb, wvT, vb, S_LEN, HDTOT, EMB);
  k_rope<<<16384, 256, 0, stream>>>(qb, kb, ang);
  k_transpose_v<<<dim3(32, 64), 256, 0, stream>>>(vb, vtb);
  k_attn<<<dim3(T_TILES, NH), 256, 0, stream>>>(qb, kb, vtb, anch, attn);
  k_gemm<false><<<dim3(16, 32), 256, 0, stream>>>(attn, woT, d_out, S_LEN, EMB, HDTOT);
}

// Round 6
// 411.088 us; speedup vs baseline: 1.6161x; 1.1993x over previous
//
#include <hip/hip_runtime.h>
#include <stdint.h>

typedef unsigned short u16;
typedef unsigned int u32;

#define S_LEN 4096
#define EMB 2048
#define NH 16
#define HD 128
#define HDTOT 2048
#define T_TILES 32
#define KANCH 8
#define SM_SCALE 0.088388347648318447f

typedef __bf16 bf16x8 __attribute__((ext_vector_type(8)));
typedef float f32x4 __attribute__((ext_vector_type(4)));

typedef const __attribute__((address_space(1))) u32 ga_u32;
typedef __attribute__((address_space(3))) u32 lds_u32;

__device__ __forceinline__ u16 f2bf(float f) {
  u32 b = __builtin_bit_cast(u32, f);
  b = (b + 0x7FFFu + ((b >> 16) & 1u)) >> 16;
  return (u16)b;
}
__device__ __forceinline__ float bf2f(u16 u) {
  return __builtin_bit_cast(float, ((u32)u) << 16);
}
__device__ __forceinline__ f32x4 mfma16(bf16x8 a, bf16x8 b, f32x4 c) {
  return __builtin_amdgcn_mfma_f32_16x16x32_bf16(a, b, c, 0, 0, 0);
}

// ---------------- x: fp32 -> bf16 ----------------
__global__ __launch_bounds__(256) void k_convert_x(const float* __restrict__ x,
                                                   u16* __restrict__ xb) {
  int i = (blockIdx.x * 256 + threadIdx.x) * 4;
  float4 v = *(const float4*)(x + i);
  ushort4 o;
  o.x = f2bf(v.x); o.y = f2bf(v.y); o.z = f2bf(v.z); o.w = f2bf(v.w);
  *(ushort4*)(xb + i) = o;
}

// ------- weights: [K=2048][N=2048] fp32 -> [N][K] bf16 (B^T for gemm) -------
__global__ __launch_bounds__(256) void k_transpose_w(
    const float* __restrict__ w0, const float* __restrict__ w1,
    const float* __restrict__ w2, const float* __restrict__ w3,
    u16* __restrict__ o0, u16* __restrict__ o1,
    u16* __restrict__ o2, u16* __restrict__ o3) {
  const float* w; u16* o;
  if (blockIdx.z == 0)      { w = w0; o = o0; }
  else if (blockIdx.z == 1) { w = w1; o = o1; }
  else if (blockIdx.z == 2) { w = w2; o = o2; }
  else                      { w = w3; o = o3; }
  __shared__ float tile[64][68];
  int n0 = blockIdx.x * 64, k0 = blockIdx.y * 64;
  int tid = threadIdx.x;
  int r = tid >> 4, cq = (tid & 15) << 2;
  for (int p = 0; p < 4; ++p) {
    float4 v = *(const float4*)(w + (size_t)(k0 + r + p * 16) * EMB + n0 + cq);
    tile[r + p * 16][cq + 0] = v.x;
    tile[r + p * 16][cq + 1] = v.y;
    tile[r + p * 16][cq + 2] = v.z;
    tile[r + p * 16][cq + 3] = v.w;
  }
  __syncthreads();
  for (int p = 0; p < 4; ++p) {
    int rn = r + p * 16;
    ushort4 u;
    u.x = f2bf(tile[cq + 0][rn]);
    u.y = f2bf(tile[cq + 1][rn]);
    u.z = f2bf(tile[cq + 2][rn]);
    u.w = f2bf(tile[cq + 3][rn]);
    *(ushort4*)(o + (size_t)(n0 + rn) * EMB + k0 + cq) = u;
  }
}

// ------- v: [S][HDTOT] bf16 -> vT [HDTOT][S] bf16 -------
__global__ __launch_bounds__(256) void k_transpose_v(const u16* __restrict__ v,
                                                     u16* __restrict__ vt) {
  __shared__ u16 tile[64][72];
  int n0 = blockIdx.x * 64, s0 = blockIdx.y * 64;
  int tid = threadIdx.x;
  int r = tid >> 4, cq = (tid & 15) << 2;
  for (int p = 0; p < 4; ++p) {
    ushort4 u = *(const ushort4*)(v + (size_t)(s0 + r + p * 16) * HDTOT + n0 + cq);
    tile[r + p * 16][cq + 0] = u.x;
    tile[r + p * 16][cq + 1] = u.y;
    tile[r + p * 16][cq + 2] = u.z;
    tile[r + p * 16][cq + 3] = u.w;
  }
  __syncthreads();
  for (int p = 0; p < 4; ++p) {
    int rn = r + p * 16;
    ushort4 o;
    o.x = tile[cq + 0][rn];
    o.y = tile[cq + 1][rn];
    o.z = tile[cq + 2][rn];
    o.w = tile[cq + 3][rn];
    *(ushort4*)(vt + (size_t)(n0 + rn) * S_LEN + s0 + cq) = o;
  }
}

// ------- m97-style bf16 GEMM core (128x128 tile, BK=32) -------
template <bool BF16OUT>
__device__ __forceinline__ void gemm_body(const u16* __restrict__ A,
                                          const u16* __restrict__ Bt,
                                          void* __restrict__ Cv,
                                          int N, int K, int m0, int n0,
                                          u16* As, u16* Bs) {
  const int tid = threadIdx.x;
  const int lane = tid & 63, wave = tid >> 6;
  const int quad = lane >> 4, l16 = lane & 15;
  const int wm = (wave >> 1) * 64, wn = (wave & 1) * 64;
  f32x4 acc[4][4] = {};

  const int flat0 = wave * 1024 + lane * 16;  // byte offset within 8KB tile
  for (int kt = 0; kt < K; kt += 32) {
    for (int half = 0; half < 2; ++half) {
      int flat = flat0 + half * 4096;
      int row = flat >> 6, colb = flat & 63;
      const char* ga = (const char*)A + ((size_t)(m0 + row) * K + kt) * 2 + colb;
      const char* gb = (const char*)Bt + ((size_t)(n0 + row) * K + kt) * 2 + colb;
      int loff = wave * 1024 + half * 4096;  // wave-uniform LDS byte offset
      __builtin_amdgcn_global_load_lds((ga_u32*)ga, (lds_u32*)((char*)As + loff), 16, 0, 0);
      __builtin_amdgcn_global_load_lds((ga_u32*)gb, (lds_u32*)((char*)Bs + loff), 16, 0, 0);
    }
    __syncthreads();
    bf16x8 af[4], bfr[4];
    for (int mt = 0; mt < 4; ++mt)
      af[mt] = *(const bf16x8*)(As + (wm + mt * 16 + l16) * 32 + quad * 8);
    for (int nt = 0; nt < 4; ++nt)
      bfr[nt] = *(const bf16x8*)(Bs + (wn + nt * 16 + l16) * 32 + quad * 8);
    for (int mt = 0; mt < 4; ++mt)
      for (int nt = 0; nt < 4; ++nt)
        acc[mt][nt] = mfma16(af[mt], bfr[nt], acc[mt][nt]);
    __syncthreads();
  }
  for (int mt = 0; mt < 4; ++mt) {
    int row = m0 + wm + mt * 16 + quad * 4;
    for (int nt = 0; nt < 4; ++nt) {
      int col = n0 + wn + nt * 16 + l16;
      for (int r = 0; r < 4; ++r) {
        if (BF16OUT)
          ((u16*)Cv)[(size_t)(row + r) * N + col] = f2bf(acc[mt][nt][r]);
        else
          ((float*)Cv)[(size_t)(row + r) * N + col] = acc[mt][nt][r];
      }
    }
  }
}

template <bool BF16OUT>
__global__ __launch_bounds__(256) void k_gemm(const u16* __restrict__ A,
                                              const u16* __restrict__ Bt,
                                              void* __restrict__ Cv,
                                              int N, int K) {
  __shared__ __align__(16) u16 As[128 * 32];
  __shared__ __align__(16) u16 Bs[128 * 32];
  gemm_body<BF16OUT>(A, Bt, Cv, N, K, blockIdx.y * 128, blockIdx.x * 128, As, Bs);
}

// ------- fused QKV GEMM: one dispatch, B^T = [wqT;wkT;wvT] (contiguous) ----
// blockIdx.x in [0,48): region = x>>4 selects q/k/v output (each pitch 2048).
__global__ __launch_bounds__(256) void k_gemm_qkv(const u16* __restrict__ A,
                                                  const u16* __restrict__ Bt,
                                                  u16* __restrict__ q,
                                                  u16* __restrict__ k,
                                                  u16* __restrict__ v) {
  __shared__ __align__(16) u16 As[128 * 32];
  __shared__ __align__(16) u16 Bs[128 * 32];
  const int nb = blockIdx.x;
  u16* out = (nb < 16) ? q : ((nb < 32) ? k : v);
  // Bt row index is global (nb*128), output col is local ((nb&15)*128):
  gemm_body<true>(A, Bt + (size_t)((nb >> 4) * 2048) * EMB, out,
                  HDTOT, EMB, blockIdx.y * 128, (nb & 15) * 128, As, Bs);
}

// ------- RoPE (half-split) applied in-place to q and k -------
__global__ __launch_bounds__(256) void k_rope(u16* __restrict__ q, u16* __restrict__ k,
                                              const float* __restrict__ ang) {
  int gid = blockIdx.x * 256 + threadIdx.x;  // S*NH*64
  int s = gid >> 10;
  int h = (gid >> 6) & (NH - 1);
  int d = gid & 63;
  float a = ang[s * 64 + d];
  float sn, cs;
  __sincosf(a, &sn, &cs);
  size_t base = (size_t)s * HDTOT + h * HD + d;
  float q1 = bf2f(q[base]), q2 = bf2f(q[base + 64]);
  q[base] = f2bf(q1 * cs - q2 * sn);
  q[base + 64] = f2bf(q2 * cs + q1 * sn);
  float k1 = bf2f(k[base]), k2 = bf2f(k[base + 64]);
  k[base] = f2bf(k1 * cs - k2 * sn);
  k[base + 64] = f2bf(k2 * cs + k1 * sn);
}

// ------- swizzled LDS fragment read (128-col bf16 tile, XOR-swizzled) -------
__device__ __forceinline__ bf16x8 ldsfrag(const u16* __restrict__ sbuf, int r, int cb) {
  return *(const bf16x8*)(sbuf + r * 128 + (((cb ^ (r & 15)) << 3)));
}

// ------- block-sparse flash attention: one block per (t, h) ----------------
// R4 structure (async global_load_lds double-buffer, 1 barrier/iter, S^T
// trick, register shfl-transpose for P) at 512 threads / 8 waves: LDS still
// caps at 1 block/CU, but now 2 waves/SIMD co-schedule so ds_read/exp/shfl
// latency of one wave hides behind the other's MFMA/VALU. Each wave owns
// 16 q-rows. VGPR ~130 < 256 cap for 8 waves/CU.
__global__ __launch_bounds__(512, 1) void k_attn(const u16* __restrict__ q,
                                                 const u16* __restrict__ k,
                                                 const u16* __restrict__ vt,
                                                 const int* __restrict__ anch,
                                                 u16* __restrict__ out) {
  __shared__ __align__(16) u16 bufK[2][128 * 128];
  __shared__ __align__(16) u16 bufV[2][128 * 128];
  __shared__ int s_tj[KANCH + 1];
  __shared__ int s_nv;
  const int t = T_TILES - 1 - blockIdx.x;  // heavy (high-t) blocks first
  const int h = blockIdx.y;
  const int tid = threadIdx.x;
  const int lane = tid & 63, wave = tid >> 6;
  const int quad = lane >> 4, l16 = lane & 15;
  const int wq0 = wave * 16;

  // Per-lane global byte offsets for this wave's 4 staging chunks (1 KB each;
  // chunk ch = wave*4+p covers rows ch*4..+3). XOR swizzle folded into the
  // GLOBAL column (within-row permute: coalescing unchanged, LDS dest linear).
  int offK[4], offV[4];
#pragma unroll
  for (int p = 0; p < 4; ++p) {
    int row = (wave * 4 + p) * 4 + (lane >> 4);
    int colsw = ((lane & 15) ^ (row & 15)) << 3;
    offK[p] = (row * HDTOT + colsw) * 2;  // K/Q pitch = HDTOT elems
    offV[p] = (row * S_LEN + colsw) * 2;  // V^T pitch = S_LEN elems
  }

  if (tid == 0) {
    int nv = 0;
    for (int j = 0; j < KANCH; ++j) {
      int tj = anch[((h * T_TILES) + t) * KANCH + j];
      if (tj <= t) s_tj[nv++] = tj;  // tj > t: fully future-masked, skip
    }
    s_tj[nv++] = t;  // local/diagonal tile
    s_nv = nv;
  }

  // stage Q (tile t) into bufV[1] (free until iteration 1's V prefetch)
  {
    const char* gq = (const char*)(q + (size_t)(t * 128) * HDTOT + h * HD);
    char* lq = (char*)bufV[1] + wave * 4096;
#pragma unroll
    for (int p = 0; p < 4; ++p)
      __builtin_amdgcn_global_load_lds((ga_u32*)(gq + offK[p]),
                                       (lds_u32*)(lq + p * 1024), 16, 0, 0);
  }
  __syncthreads();  // Q arrived (vmcnt drain at barrier), s_tj visible

  bf16x8 qf[4];  // Q B-frags: lane n=l16 -> qrow wq0+l16, k-contig
#pragma unroll
  for (int ks = 0; ks < 4; ++ks)
    qf[ks] = ldsfrag(bufV[1], wq0 + l16, ks * 4 + quad);

  const int nv = s_nv;
  const char* kh = (const char*)(k + h * HD);
  const char* vh = (const char*)(vt + (size_t)(h * HD) * S_LEN);

  // issue tile 0 loads (drained at first loop barrier)
  {
    int tj0 = s_tj[0];
    const char* gk = kh + (size_t)(tj0 * 128) * (HDTOT * 2);
    const char* gv = vh + (size_t)(tj0 * 128) * 2;
    char* lk = (char*)bufK[0] + wave * 4096;
    char* lv = (char*)bufV[0] + wave * 4096;
#pragma unroll
    for (int p = 0; p < 4; ++p) {
      __builtin_amdgcn_global_load_lds((ga_u32*)(gk + offK[p]),
                                       (lds_u32*)(lk + p * 1024), 16, 0, 0);
      __builtin_amdgcn_global_load_lds((ga_u32*)(gv + offV[p]),
                                       (lds_u32*)(lv + p * 1024), 16, 0, 0);
    }
  }

  f32x4 oacc[8] = {};
  float m_st = -1e30f, l_st = 0.f;

  for (int i = 0; i < nv; ++i) {
    const int par = i & 1;
    const u16* K_c = bufK[par];
    const u16* V_c = bufV[par];
    const int tj = s_tj[i];
    const bool diag = (tj == t);

    __syncthreads();  // drains tile-i loads; WAR-protects buffer 1-par

    // prefetch tile i+1 (in flight for the whole compute phase below)
    if (i + 1 < nv) {
      int tjn = s_tj[i + 1];
      const char* gk = kh + (size_t)(tjn * 128) * (HDTOT * 2);
      const char* gv = vh + (size_t)(tjn * 128) * 2;
      char* lk = (char*)bufK[1 - par] + wave * 4096;
      char* lv = (char*)bufV[1 - par] + wave * 4096;
#pragma unroll
      for (int p = 0; p < 4; ++p) {
        __builtin_amdgcn_global_load_lds((ga_u32*)(gk + offK[p]),
                                         (lds_u32*)(lk + p * 1024), 16, 0, 0);
        __builtin_amdgcn_global_load_lds((ga_u32*)(gv + offV[p]),
                                         (lds_u32*)(lv + p * 1024), 16, 0, 0);
      }
    }

    // S^T = K·Q^T : sacc[a][r] = S[qrow=wq0+l16][key=a*16+quad*4+r]
    f32x4 sacc[8] = {};
#pragma unroll
    for (int ks = 0; ks < 4; ++ks)
#pragma unroll
      for (int a = 0; a < 8; ++a) {
        bf16x8 kf = ldsfrag(K_c, a * 16 + l16, ks * 4 + quad);
        sacc[a] = mfma16(kf, qf[ks], sacc[a]);
      }

    // online softmax: lane holds 32 keys for qrow wq0+l16
    u32 pl[8], ph[8];
    float alpha;
    {
      const int qr = wq0 + l16;
      float rmax = -1e30f;
#pragma unroll
      for (int a = 0; a < 8; ++a) {
        f32x4 s4 = sacc[a];
#pragma unroll
        for (int r = 0; r < 4; ++r) {
          float sv = s4[r] * SM_SCALE;
          if (diag && (a * 16 + quad * 4 + r > qr)) sv = -1e30f;
          s4[r] = sv;
          rmax = fmaxf(rmax, sv);
        }
        sacc[a] = s4;
      }
      rmax = fmaxf(rmax, __shfl_xor(rmax, 16));
      rmax = fmaxf(rmax, __shfl_xor(rmax, 32));
      float mnew = fmaxf(m_st, rmax);
      alpha = __expf(m_st - mnew);
      m_st = mnew;
      float rsum = 0.f;
#pragma unroll
      for (int a = 0; a < 8; ++a) {
        f32x4 s4 = sacc[a];
        float p0 = __expf(s4[0] - mnew);
        float p1 = __expf(s4[1] - mnew);
        float p2 = __expf(s4[2] - mnew);
        float p3 = __expf(s4[3] - mnew);
        rsum += (p0 + p1) + (p2 + p3);
        // pack pairs to bf16 (round via +0x8000, take high halves)
        pl[a] = __builtin_amdgcn_perm(__builtin_bit_cast(u32, p1) + 0x8000u,
                                      __builtin_bit_cast(u32, p0) + 0x8000u,
                                      0x07060302u);
        ph[a] = __builtin_amdgcn_perm(__builtin_bit_cast(u32, p3) + 0x8000u,
                                      __builtin_bit_cast(u32, p2) + 0x8000u,
                                      0x07060302u);
      }
      rsum += __shfl_xor(rsum, 16);
      rsum += __shfl_xor(rsum, 32);
      l_st = l_st * alpha + rsum;
    }

    // rescale O (O rows are quad*4+r; alpha lives at lane l16 == row)
    {
      f32x4 av;
#pragma unroll
      for (int r = 0; r < 4; ++r)
        av[r] = __shfl(alpha, (lane & 48) | (quad * 4 + r));
#pragma unroll
      for (int nt = 0; nt < 8; ++nt) {
        f32x4 o4 = oacc[nt];
        o4[0] *= av[0]; o4[1] *= av[1]; o4[2] *= av[2]; o4[3] *= av[3];
        oacc[nt] = o4;
      }
    }

    // O += P·V : A-frags via register shfl-transpose of packed P
    const int srcA = ((quad & 1) << 5) + l16;  // src lane (quad_s = 2*(quad&1))
    const int srcB = srcA + 16;
    const int hi = quad >> 1;
#pragma unroll
    for (int c = 0; c < 4; ++c) {
      u32 x0 = __shfl(pl[2 * c], srcA), x1 = __shfl(ph[2 * c], srcA);
      u32 x2 = __shfl(pl[2 * c], srcB), x3 = __shfl(ph[2 * c], srcB);
      u32 y0 = __shfl(pl[2 * c + 1], srcA), y1 = __shfl(ph[2 * c + 1], srcA);
      u32 y2 = __shfl(pl[2 * c + 1], srcB), y3 = __shfl(ph[2 * c + 1], srcB);
      uint4 w;
      w.x = hi ? y0 : x0;
      w.y = hi ? y1 : x1;
      w.z = hi ? y2 : x2;
      w.w = hi ? y3 : x3;
      bf16x8 pa = __builtin_bit_cast(bf16x8, w);
#pragma unroll
      for (int nt = 0; nt < 8; ++nt) {
        bf16x8 vf = ldsfrag(V_c, nt * 16 + l16, c * 4 + quad);
        oacc[nt] = mfma16(pa, vf, oacc[nt]);
      }
    }
  }

  // epilogue: normalize rows (1/l via shfl to O-row lanes) and store
  {
    float linv = 1.0f / l_st;
    f32x4 iv;
#pragma unroll
    for (int r = 0; r < 4; ++r)
      iv[r] = __shfl(linv, (lane & 48) | (quad * 4 + r));
#pragma unroll
    for (int r = 0; r < 4; ++r) {
      size_t srow_o = (size_t)(t * 128 + wq0 + quad * 4 + r);
#pragma unroll
      for (int nt = 0; nt < 8; ++nt)
        out[srow_o * HDTOT + h * HD + nt * 16 + l16] = f2bf(oacc[nt][r] * iv[r]);
    }
  }
}

extern "C" void kernel_launch(void* const* d_in, const int* in_sizes, int n_in,
                              void* d_out, int out_size, void* d_ws, size_t ws_size,
                              hipStream_t stream) {
  const float* x   = (const float*)d_in[0];
  const float* wq  = (const float*)d_in[1];
  const float* wk  = (const float*)d_in[2];
  const float* wv  = (const float*)d_in[3];
  const float* wo  = (const float*)d_in[4];
  const float* ang = (const float*)d_in[5];
  const int* anch  = (const int*)d_in[6];

  char* ws = (char*)d_ws;
  const size_t SZ_SE = (size_t)S_LEN * HDTOT * sizeof(u16);  // 16 MB
  const size_t SZ_W  = (size_t)EMB * EMB * sizeof(u16);      // 8 MB
  u16* xb   = (u16*)(ws);
  u16* qb   = (u16*)(ws + SZ_SE);
  u16* kb   = (u16*)(ws + 2 * SZ_SE);
  u16* vb   = (u16*)(ws + 3 * SZ_SE);
  u16* vtb  = (u16*)(ws + 4 * SZ_SE);
  u16* attn = (u16*)(ws + 5 * SZ_SE);
  u16* wqT  = (u16*)(ws + 6 * SZ_SE);            // wqT,wkT,wvT contiguous ->
  u16* wkT  = (u16*)(ws + 6 * SZ_SE + SZ_W);     // single B^T for fused QKV
  u16* wvT  = (u16*)(ws + 6 * SZ_SE + 2 * SZ_W);
  u16* woT  = (u16*)(ws + 6 * SZ_SE + 3 * SZ_W);

  k_convert_x<<<8192, 256, 0, stream>>>(x, xb);
  k_transpose_w<<<dim3(32, 32, 4), 256, 0, stream>>>(wq, wk, wv, wo, wqT, wkT, wvT, woT);
  k_gemm_qkv<<<dim3(48, 32), 256, 0, stream>>>(xb, wqT, qb, kb, vb);
  k_rope<<<16384, 256, 0, stream>>>(qb, kb, ang);
  k_transpose_v<<<dim3(32, 64), 256, 0, stream>>>(vb, vtb);
  k_attn<<<dim3(T_TILES, NH), 512, 0, stream>>>(qb, kb, vtb, anch, attn);
  // WO projection: output is [S_LEN x EMB], so N = EMB (R5 bug: passed S_LEN)
  k_gemm<false><<<dim3(16, 32), 256, 0, stream>>>(attn, woT, d_out, EMB, HDTOT);
}

// Round 7
// 400.976 us; speedup vs baseline: 1.6568x; 1.0252x over previous
//
#include <hip/hip_runtime.h>
#include <stdint.h>

typedef unsigned short u16;
typedef unsigned int u32;

#define S_LEN 4096
#define EMB 2048
#define NH 16
#define HD 128
#define HDTOT 2048
#define T_TILES 32
#define KANCH 8
#define SM_SCALE 0.088388347648318447f

typedef __bf16 bf16x8 __attribute__((ext_vector_type(8)));
typedef float f32x4 __attribute__((ext_vector_type(4)));

typedef const __attribute__((address_space(1))) u32 ga_u32;
typedef __attribute__((address_space(3))) u32 lds_u32;

__device__ __forceinline__ u16 f2bf(float f) {
  u32 b = __builtin_bit_cast(u32, f);
  b = (b + 0x7FFFu + ((b >> 16) & 1u)) >> 16;
  return (u16)b;
}
__device__ __forceinline__ float bf2f(u16 u) {
  return __builtin_bit_cast(float, ((u32)u) << 16);
}
__device__ __forceinline__ f32x4 mfma16(bf16x8 a, bf16x8 b, f32x4 c) {
  return __builtin_amdgcn_mfma_f32_16x16x32_bf16(a, b, c, 0, 0, 0);
}

// ---------------- x: fp32 -> bf16 ----------------
__global__ __launch_bounds__(256) void k_convert_x(const float* __restrict__ x,
                                                   u16* __restrict__ xb) {
  int i = (blockIdx.x * 256 + threadIdx.x) * 4;
  float4 v = *(const float4*)(x + i);
  ushort4 o;
  o.x = f2bf(v.x); o.y = f2bf(v.y); o.z = f2bf(v.z); o.w = f2bf(v.w);
  *(ushort4*)(xb + i) = o;
}

// ------- weights: [K=2048][N=2048] fp32 -> [N][K] bf16 (B^T for gemm) -------
__global__ __launch_bounds__(256) void k_transpose_w(
    const float* __restrict__ w0, const float* __restrict__ w1,
    const float* __restrict__ w2, const float* __restrict__ w3,
    u16* __restrict__ o0, u16* __restrict__ o1,
    u16* __restrict__ o2, u16* __restrict__ o3) {
  const float* w; u16* o;
  if (blockIdx.z == 0)      { w = w0; o = o0; }
  else if (blockIdx.z == 1) { w = w1; o = o1; }
  else if (blockIdx.z == 2) { w = w2; o = o2; }
  else                      { w = w3; o = o3; }
  __shared__ float tile[64][68];
  int n0 = blockIdx.x * 64, k0 = blockIdx.y * 64;
  int tid = threadIdx.x;
  int r = tid >> 4, cq = (tid & 15) << 2;
  for (int p = 0; p < 4; ++p) {
    float4 v = *(const float4*)(w + (size_t)(k0 + r + p * 16) * EMB + n0 + cq);
    tile[r + p * 16][cq + 0] = v.x;
    tile[r + p * 16][cq + 1] = v.y;
    tile[r + p * 16][cq + 2] = v.z;
    tile[r + p * 16][cq + 3] = v.w;
  }
  __syncthreads();
  for (int p = 0; p < 4; ++p) {
    int rn = r + p * 16;
    ushort4 u;
    u.x = f2bf(tile[cq + 0][rn]);
    u.y = f2bf(tile[cq + 1][rn]);
    u.z = f2bf(tile[cq + 2][rn]);
    u.w = f2bf(tile[cq + 3][rn]);
    *(ushort4*)(o + (size_t)(n0 + rn) * EMB + k0 + cq) = u;
  }
}

// ------- v: [S][HDTOT] bf16 -> vT [HDTOT][S] bf16 -------
__global__ __launch_bounds__(256) void k_transpose_v(const u16* __restrict__ v,
                                                     u16* __restrict__ vt) {
  __shared__ u16 tile[64][72];
  int n0 = blockIdx.x * 64, s0 = blockIdx.y * 64;
  int tid = threadIdx.x;
  int r = tid >> 4, cq = (tid & 15) << 2;
  for (int p = 0; p < 4; ++p) {
    ushort4 u = *(const ushort4*)(v + (size_t)(s0 + r + p * 16) * HDTOT + n0 + cq);
    tile[r + p * 16][cq + 0] = u.x;
    tile[r + p * 16][cq + 1] = u.y;
    tile[r + p * 16][cq + 2] = u.z;
    tile[r + p * 16][cq + 3] = u.w;
  }
  __syncthreads();
  for (int p = 0; p < 4; ++p) {
    int rn = r + p * 16;
    ushort4 o;
    o.x = tile[cq + 0][rn];
    o.y = tile[cq + 1][rn];
    o.z = tile[cq + 2][rn];
    o.w = tile[cq + 3][rn];
    *(ushort4*)(vt + (size_t)(n0 + rn) * S_LEN + s0 + cq) = o;
  }
}

// ------- m97-style bf16 GEMM core (128x128 tile, BK=32) -------
template <bool BF16OUT>
__device__ __forceinline__ void gemm_body(const u16* __restrict__ A,
                                          const u16* __restrict__ Bt,
                                          void* __restrict__ Cv,
                                          int N, int K, int m0, int n0,
                                          u16* As, u16* Bs) {
  const int tid = threadIdx.x;
  const int lane = tid & 63, wave = tid >> 6;
  const int quad = lane >> 4, l16 = lane & 15;
  const int wm = (wave >> 1) * 64, wn = (wave & 1) * 64;
  f32x4 acc[4][4] = {};

  const int flat0 = wave * 1024 + lane * 16;  // byte offset within 8KB tile
  for (int kt = 0; kt < K; kt += 32) {
    for (int half = 0; half < 2; ++half) {
      int flat = flat0 + half * 4096;
      int row = flat >> 6, colb = flat & 63;
      const char* ga = (const char*)A + ((size_t)(m0 + row) * K + kt) * 2 + colb;
      const char* gb = (const char*)Bt + ((size_t)(n0 + row) * K + kt) * 2 + colb;
      int loff = wave * 1024 + half * 4096;  // wave-uniform LDS byte offset
      __builtin_amdgcn_global_load_lds((ga_u32*)ga, (lds_u32*)((char*)As + loff), 16, 0, 0);
      __builtin_amdgcn_global_load_lds((ga_u32*)gb, (lds_u32*)((char*)Bs + loff), 16, 0, 0);
    }
    __syncthreads();
    bf16x8 af[4], bfr[4];
    for (int mt = 0; mt < 4; ++mt)
      af[mt] = *(const bf16x8*)(As + (wm + mt * 16 + l16) * 32 + quad * 8);
    for (int nt = 0; nt < 4; ++nt)
      bfr[nt] = *(const bf16x8*)(Bs + (wn + nt * 16 + l16) * 32 + quad * 8);
    for (int mt = 0; mt < 4; ++mt)
      for (int nt = 0; nt < 4; ++nt)
        acc[mt][nt] = mfma16(af[mt], bfr[nt], acc[mt][nt]);
    __syncthreads();
  }
  for (int mt = 0; mt < 4; ++mt) {
    int row = m0 + wm + mt * 16 + quad * 4;
    for (int nt = 0; nt < 4; ++nt) {
      int col = n0 + wn + nt * 16 + l16;
      for (int r = 0; r < 4; ++r) {
        if (BF16OUT)
          ((u16*)Cv)[(size_t)(row + r) * N + col] = f2bf(acc[mt][nt][r]);
        else
          ((float*)Cv)[(size_t)(row + r) * N + col] = acc[mt][nt][r];
      }
    }
  }
}

template <bool BF16OUT>
__global__ __launch_bounds__(256) void k_gemm(const u16* __restrict__ A,
                                              const u16* __restrict__ Bt,
                                              void* __restrict__ Cv,
                                              int N, int K) {
  __shared__ __align__(16) u16 As[128 * 32];
  __shared__ __align__(16) u16 Bs[128 * 32];
  gemm_body<BF16OUT>(A, Bt, Cv, N, K, blockIdx.y * 128, blockIdx.x * 128, As, Bs);
}

// ------- fused QKV GEMM: one dispatch, B^T = [wqT;wkT;wvT] (contiguous) ----
// blockIdx.x in [0,48): region = x>>4 selects q/k/v output (each pitch 2048).
__global__ __launch_bounds__(256) void k_gemm_qkv(const u16* __restrict__ A,
                                                  const u16* __restrict__ Bt,
                                                  u16* __restrict__ q,
                                                  u16* __restrict__ k,
                                                  u16* __restrict__ v) {
  __shared__ __align__(16) u16 As[128 * 32];
  __shared__ __align__(16) u16 Bs[128 * 32];
  const int nb = blockIdx.x;
  u16* out = (nb < 16) ? q : ((nb < 32) ? k : v);
  // Bt row index is global (nb*128), output col is local ((nb&15)*128):
  gemm_body<true>(A, Bt + (size_t)((nb >> 4) * 2048) * EMB, out,
                  HDTOT, EMB, blockIdx.y * 128, (nb & 15) * 128, As, Bs);
}

// ------- RoPE (half-split), vectorized 8-wide, in-place on q and k -------
__global__ __launch_bounds__(256) void k_rope(u16* __restrict__ q, u16* __restrict__ k,
                                              const float* __restrict__ ang) {
  int gid = blockIdx.x * 256 + threadIdx.x;  // S*NH*8 = 524288 threads
  int s = gid >> 7;
  int h = (gid >> 3) & (NH - 1);
  int dq = (gid & 7) << 3;  // 0..56, 8 dims per thread
  const float* ap = ang + s * 64 + dq;
  float4 a0 = *(const float4*)(ap);
  float4 a1 = *(const float4*)(ap + 4);
  float sn[8], cs[8];
  __sincosf(a0.x, &sn[0], &cs[0]);
  __sincosf(a0.y, &sn[1], &cs[1]);
  __sincosf(a0.z, &sn[2], &cs[2]);
  __sincosf(a0.w, &sn[3], &cs[3]);
  __sincosf(a1.x, &sn[4], &cs[4]);
  __sincosf(a1.y, &sn[5], &cs[5]);
  __sincosf(a1.z, &sn[6], &cs[6]);
  __sincosf(a1.w, &sn[7], &cs[7]);
  size_t base = (size_t)s * HDTOT + h * HD + dq;
  u16* ptrs[2] = {q, k};
#pragma unroll
  for (int a = 0; a < 2; ++a) {
    u16* p = ptrs[a] + base;
    ushort4 x1a = *(const ushort4*)(p);
    ushort4 x1b = *(const ushort4*)(p + 4);
    ushort4 x2a = *(const ushort4*)(p + 64);
    ushort4 x2b = *(const ushort4*)(p + 68);
    u16 v1[8] = {x1a.x, x1a.y, x1a.z, x1a.w, x1b.x, x1b.y, x1b.z, x1b.w};
    u16 v2[8] = {x2a.x, x2a.y, x2a.z, x2a.w, x2b.x, x2b.y, x2b.z, x2b.w};
    u16 o1[8], o2[8];
#pragma unroll
    for (int e = 0; e < 8; ++e) {
      float f1 = bf2f(v1[e]), f2 = bf2f(v2[e]);
      o1[e] = f2bf(f1 * cs[e] - f2 * sn[e]);
      o2[e] = f2bf(f2 * cs[e] + f1 * sn[e]);
    }
    *(ushort4*)(p)      = make_ushort4(o1[0], o1[1], o1[2], o1[3]);
    *(ushort4*)(p + 4)  = make_ushort4(o1[4], o1[5], o1[6], o1[7]);
    *(ushort4*)(p + 64) = make_ushort4(o2[0], o2[1], o2[2], o2[3]);
    *(ushort4*)(p + 68) = make_ushort4(o2[4], o2[5], o2[6], o2[7]);
  }
}

// ------- swizzled LDS fragment reads -------
// 128-col bf16 tile (Q staging / K half-tiles), 16-group XOR swizzle:
__device__ __forceinline__ bf16x8 ldsfrag(const u16* __restrict__ sbuf, int r, int cb) {
  return *(const bf16x8*)(sbuf + r * 128 + (((cb ^ (r & 15)) << 3)));
}
// 64-col bf16 tile (V^T half-tiles), 8-group XOR swizzle:
__device__ __forceinline__ bf16x8 ldsfragV(const u16* __restrict__ sbuf, int r, int cb) {
  return *(const bf16x8*)(sbuf + r * 64 + (((cb ^ (r & 7)) << 3)));
}

// ------- block-sparse flash attention: one block per (t, h) ----------------
// R6 structure (async global_load_lds dbuf, 1 barrier/iter, S^T trick,
// register shfl-transpose for P) with 64-KEY HALF-TILES: bufK 2x(64x128),
// bufV 2x(128x64) = 64KB LDS -> 2 blocks/CU -> 4 waves/SIMD (was 2).
// Iterations double, per-iter work halves; latency hiding ~2x. VGPR must
// stay <=128 for 2-block residency: __launch_bounds__(512,4).
__global__ __launch_bounds__(512, 4) void k_attn(const u16* __restrict__ q,
                                                 const u16* __restrict__ k,
                                                 const u16* __restrict__ vt,
                                                 const int* __restrict__ anch,
                                                 u16* __restrict__ out) {
  __shared__ __align__(16) u16 bufK[2][64 * 128];  // keys x dims (Q overlay at start)
  __shared__ __align__(16) u16 bufV[2][128 * 64];  // dims x keys
  __shared__ int s_tj[KANCH + 1];
  __shared__ int s_nv;
  const int t = T_TILES - 1 - blockIdx.x;  // heavy (high-t) blocks first
  const int h = blockIdx.y;
  const int tid = threadIdx.x;
  const int lane = tid & 63, wave = tid >> 6;
  const int quad = lane >> 4, l16 = lane & 15;
  const int wq0 = wave * 16;

  // K half-tile staging: 2 chunks/wave, rows 0..63 (keys), 128-col swizzle
  int offK[2], offV[2];
#pragma unroll
  for (int p = 0; p < 2; ++p) {
    int krow = (wave * 2 + p) * 4 + (lane >> 4);
    int kcol = ((lane & 15) ^ (krow & 15)) << 3;
    offK[p] = (krow * HDTOT + kcol) * 2;
    // V^T half-tile: 2 chunks/wave, rows 0..127 (dims), 64-col swizzle
    int vrow = (wave * 2 + p) * 8 + (lane >> 3);
    int vcol = ((lane & 7) ^ (vrow & 7)) << 3;
    offV[p] = (vrow * S_LEN + vcol) * 2;
  }

  if (tid == 0) {
    int nv = 0;
    for (int j = 0; j < KANCH; ++j) {
      int tj = anch[((h * T_TILES) + t) * KANCH + j];
      if (tj <= t) s_tj[nv++] = tj;  // tj > t: fully future-masked, skip
    }
    s_tj[nv++] = t;  // local/diagonal tile
    s_nv = nv;
  }

  // stage full Q tile (128x128) into bufK[0]+bufK[1] (contiguous 32KB)
  {
    const char* gq = (const char*)(q + (size_t)(t * 128) * HDTOT + h * HD);
    char* lq = (char*)bufK + wave * 4096;
#pragma unroll
    for (int p = 0; p < 4; ++p) {
      int qrow = (wave * 4 + p) * 4 + (lane >> 4);
      int qcol = ((lane & 15) ^ (qrow & 15)) << 3;
      __builtin_amdgcn_global_load_lds((ga_u32*)(gq + (qrow * HDTOT + qcol) * 2),
                                       (lds_u32*)(lq + p * 1024), 16, 0, 0);
    }
  }
  __syncthreads();  // Q arrived; s_tj visible

  bf16x8 qf[4];  // Q B-frags: qrow = wq0+l16, k-contig (128-col tile view)
#pragma unroll
  for (int ks = 0; ks < 4; ++ks)
    qf[ks] = ldsfrag(&bufK[0][0], wq0 + l16, ks * 4 + quad);

  const int nv2 = 2 * s_nv;
  const char* kh = (const char*)(k + h * HD);
  const char* vh = (const char*)(vt + (size_t)(h * HD) * S_LEN);

  __syncthreads();  // all waves done reading Q before K0 DMA overwrites bufK[0]

  // issue half-tile 0 loads (drained at first loop barrier)
  {
    int key0 = s_tj[0] * 128;  // half 0
    const char* gk = kh + (size_t)key0 * (HDTOT * 2);
    const char* gv = vh + (size_t)key0 * 2;
    char* lk = (char*)bufK[0] + wave * 2048;
    char* lv = (char*)bufV[0] + wave * 2048;
#pragma unroll
    for (int p = 0; p < 2; ++p) {
      __builtin_amdgcn_global_load_lds((ga_u32*)(gk + offK[p]),
                                       (lds_u32*)(lk + p * 1024), 16, 0, 0);
      __builtin_amdgcn_global_load_lds((ga_u32*)(gv + offV[p]),
                                       (lds_u32*)(lv + p * 1024), 16, 0, 0);
    }
  }

  f32x4 oacc[8] = {};
  float m_st = -1e30f, l_st = 0.f;

  for (int i = 0; i < nv2; ++i) {
    const int par = i & 1;
    const u16* K_c = bufK[par];
    const u16* V_c = bufV[par];
    const int tj = s_tj[i >> 1];
    const int half = i & 1;
    const bool diag = (tj == t);

    __syncthreads();  // drains half-tile-i loads; WAR-protects buffer 1-par

    // prefetch half-tile i+1 (in flight for the whole compute phase below)
    if (i + 1 < nv2) {
      int inx = i + 1;
      int key0 = s_tj[inx >> 1] * 128 + (inx & 1) * 64;
      const char* gk = kh + (size_t)key0 * (HDTOT * 2);
      const char* gv = vh + (size_t)key0 * 2;
      char* lk = (char*)bufK[1 - par] + wave * 2048;
      char* lv = (char*)bufV[1 - par] + wave * 2048;
#pragma unroll
      for (int p = 0; p < 2; ++p) {
        __builtin_amdgcn_global_load_lds((ga_u32*)(gk + offK[p]),
                                         (lds_u32*)(lk + p * 1024), 16, 0, 0);
        __builtin_amdgcn_global_load_lds((ga_u32*)(gv + offV[p]),
                                         (lds_u32*)(lv + p * 1024), 16, 0, 0);
      }
    }

    // S^T = K·Q^T : sacc[a][r] = S[qrow=wq0+l16][key_local=a*16+quad*4+r]
    f32x4 sacc[4] = {};
#pragma unroll
    for (int ks = 0; ks < 4; ++ks)
#pragma unroll
      for (int a = 0; a < 4; ++a) {
        bf16x8 kf = ldsfrag(K_c, a * 16 + l16, ks * 4 + quad);
        sacc[a] = mfma16(kf, qf[ks], sacc[a]);
      }

    // online softmax: lane holds 16 keys for qrow wq0+l16
    u32 pl[4], ph[4];
    float alpha;
    {
      const int qr = wq0 + l16;
      const int kb = half * 64;
      float rmax = -1e30f;
#pragma unroll
      for (int a = 0; a < 4; ++a) {
        f32x4 s4 = sacc[a];
#pragma unroll
        for (int r = 0; r < 4; ++r) {
          float sv = s4[r] * SM_SCALE;
          if (diag && (kb + a * 16 + quad * 4 + r > qr)) sv = -1e30f;
          s4[r] = sv;
          rmax = fmaxf(rmax, sv);
        }
        sacc[a] = s4;
      }
      rmax = fmaxf(rmax, __shfl_xor(rmax, 16));
      rmax = fmaxf(rmax, __shfl_xor(rmax, 32));
      float mnew = fmaxf(m_st, rmax);
      alpha = __expf(m_st - mnew);
      m_st = mnew;
      float rsum = 0.f;
#pragma unroll
      for (int a = 0; a < 4; ++a) {
        f32x4 s4 = sacc[a];
        float p0 = __expf(s4[0] - mnew);
        float p1 = __expf(s4[1] - mnew);
        float p2 = __expf(s4[2] - mnew);
        float p3 = __expf(s4[3] - mnew);
        rsum += (p0 + p1) + (p2 + p3);
        pl[a] = __builtin_amdgcn_perm(__builtin_bit_cast(u32, p1) + 0x8000u,
                                      __builtin_bit_cast(u32, p0) + 0x8000u,
                                      0x07060302u);
        ph[a] = __builtin_amdgcn_perm(__builtin_bit_cast(u32, p3) + 0x8000u,
                                      __builtin_bit_cast(u32, p2) + 0x8000u,
                                      0x07060302u);
      }
      rsum += __shfl_xor(rsum, 16);
      rsum += __shfl_xor(rsum, 32);
      l_st = l_st * alpha + rsum;
    }

    // rescale O (O rows are quad*4+r; alpha lives at lane l16 == row)
    {
      f32x4 av;
#pragma unroll
      for (int r = 0; r < 4; ++r)
        av[r] = __shfl(alpha, (lane & 48) | (quad * 4 + r));
#pragma unroll
      for (int nt = 0; nt < 8; ++nt) {
        f32x4 o4 = oacc[nt];
        o4[0] *= av[0]; o4[1] *= av[1]; o4[2] *= av[2]; o4[3] *= av[3];
        oacc[nt] = o4;
      }
    }

    // O += P·V : A-frags via register shfl-transpose of packed P
    const int srcA = ((quad & 1) << 5) + l16;
    const int srcB = srcA + 16;
    const int hi = quad >> 1;
#pragma unroll
    for (int c = 0; c < 2; ++c) {
      u32 x0 = __shfl(pl[2 * c], srcA), x1 = __shfl(ph[2 * c], srcA);
      u32 x2 = __shfl(pl[2 * c], srcB), x3 = __shfl(ph[2 * c], srcB);
      u32 y0 = __shfl(pl[2 * c + 1], srcA), y1 = __shfl(ph[2 * c + 1], srcA);
      u32 y2 = __shfl(pl[2 * c + 1], srcB), y3 = __shfl(ph[2 * c + 1], srcB);
      uint4 w;
      w.x = hi ? y0 : x0;
      w.y = hi ? y1 : x1;
      w.z = hi ? y2 : x2;
      w.w = hi ? y3 : x3;
      bf16x8 pa = __builtin_bit_cast(bf16x8, w);
#pragma unroll
      for (int nt = 0; nt < 8; ++nt) {
        bf16x8 vf = ldsfragV(V_c, nt * 16 + l16, c * 4 + quad);
        oacc[nt] = mfma16(pa, vf, oacc[nt]);
      }
    }
  }

  // epilogue: normalize rows (1/l via shfl to O-row lanes) and store
  {
    float linv = 1.0f / l_st;
    f32x4 iv;
#pragma unroll
    for (int r = 0; r < 4; ++r)
      iv[r] = __shfl(linv, (lane & 48) | (quad * 4 + r));
#pragma unroll
    for (int r = 0; r < 4; ++r) {
      size_t srow_o = (size_t)(t * 128 + wq0 + quad * 4 + r);
#pragma unroll
      for (int nt = 0; nt < 8; ++nt)
        out[srow_o * HDTOT + h * HD + nt * 16 + l16] = f2bf(oacc[nt][r] * iv[r]);
    }
  }
}

extern "C" void kernel_launch(void* const* d_in, const int* in_sizes, int n_in,
                              void* d_out, int out_size, void* d_ws, size_t ws_size,
                              hipStream_t stream) {
  const float* x   = (const float*)d_in[0];
  const float* wq  = (const float*)d_in[1];
  const float* wk  = (const float*)d_in[2];
  const float* wv  = (const float*)d_in[3];
  const float* wo  = (const float*)d_in[4];
  const float* ang = (const float*)d_in[5];
  const int* anch  = (const int*)d_in[6];

  char* ws = (char*)d_ws;
  const size_t SZ_SE = (size_t)S_LEN * HDTOT * sizeof(u16);  // 16 MB
  const size_t SZ_W  = (size_t)EMB * EMB * sizeof(u16);      // 8 MB
  u16* xb   = (u16*)(ws);
  u16* qb   = (u16*)(ws + SZ_SE);
  u16* kb   = (u16*)(ws + 2 * SZ_SE);
  u16* vb   = (u16*)(ws + 3 * SZ_SE);
  u16* vtb  = (u16*)(ws + 4 * SZ_SE);
  u16* attn = (u16*)(ws + 5 * SZ_SE);
  u16* wqT  = (u16*)(ws + 6 * SZ_SE);            // wqT,wkT,wvT contiguous ->
  u16* wkT  = (u16*)(ws + 6 * SZ_SE + SZ_W);     // single B^T for fused QKV
  u16* wvT  = (u16*)(ws + 6 * SZ_SE + 2 * SZ_W);
  u16* woT  = (u16*)(ws + 6 * SZ_SE + 3 * SZ_W);

  k_convert_x<<<8192, 256, 0, stream>>>(x, xb);
  k_transpose_w<<<dim3(32, 32, 4), 256, 0, stream>>>(wq, wk, wv, wo, wqT, wkT, wvT, woT);
  k_gemm_qkv<<<dim3(48, 32), 256, 0, stream>>>(xb, wqT, qb, kb, vb);
  k_rope<<<2048, 256, 0, stream>>>(qb, kb, ang);
  k_transpose_v<<<dim3(32, 64), 256, 0, stream>>>(vb, vtb);
  k_attn<<<dim3(T_TILES, NH), 512, 0, stream>>>(qb, kb, vtb, anch, attn);
  k_gemm<false><<<dim3(16, 32), 256, 0, stream>>>(attn, woT, d_out, EMB, HDTOT);
}